// Round 34
// baseline (472.788 us; speedup 1.0000x reference)
//
#include <hip/hip_runtime.h>
#include <math.h>

#define NN 8192
#define DF 768
#define NE_ 262144
#define DIM 1536
#define DSN 16
#define NCH 128
#define CL  64   // NN / NCH
#define CT  64   // conv time-block

typedef short short8 __attribute__((ext_vector_type(8)));
typedef float f32x4 __attribute__((ext_vector_type(4)));

__device__ __forceinline__ float bf2f(unsigned short u){
  unsigned int v = ((unsigned int)u) << 16; float f; __builtin_memcpy(&f, &v, 4); return f;
}
__device__ __forceinline__ unsigned short f2bf(float f){
  unsigned int x; __builtin_memcpy(&x, &f, 4);
  x += 0x7fffu + ((x >> 16) & 1u);
  return (unsigned short)(x >> 16);
}
#define EXP2RAW(x) __builtin_amdgcn_exp2f(x)   // single v_exp_f32
#define LOG2E 1.44269504088896f
#define LN2   0.69314718055995f
#define H8SCALE 64.f
// fast sigmoid: native exp2 + rcp
__device__ __forceinline__ float sigmoidf_(float x){
  return 1.f/(1.f + EXP2RAW(-x*LOG2E));
}
// fast softplus: ln2 * log2(1 + 2^(v*log2e)); exact passthrough for large v
__device__ __forceinline__ float softplusf_(float v){
  if (v > 20.f) return v;
  return LN2 * __log2f(1.f + EXP2RAW(v*LOG2E));
}

// ---- fp8 e4m3fn encode ----
__device__ __forceinline__ unsigned char f2fp8(float v){
  float y = v * H8SCALE;
#if __has_builtin(__builtin_amdgcn_cvt_pk_fp8_f32)
  return (unsigned char)(__builtin_amdgcn_cvt_pk_fp8_f32(y, y, 0, false) & 0xff);
#else
  unsigned int u; __builtin_memcpy(&u, &y, 4);
  unsigned char s = (unsigned char)((u >> 24) & 0x80);
  float a = fabsf(y);
  if (a >= 448.f) return (unsigned char)(s | 0x7E);
  if (a < 0x1p-10f) return s;
  unsigned int ab = u & 0x7fffffffu;
  int ef = (int)(ab >> 23) - 127;
  int qe = ef - 3; if (qe < -9) qe = -9;
  float q; { unsigned int qb = (unsigned int)(qe + 127) << 23; __builtin_memcpy(&q, &qb, 4); }
  float n = rintf(a / q);
  float m = n * q;
  unsigned int mb; __builtin_memcpy(&mb, &m, 4);
  int E = (int)(mb >> 23) - 127 + 7;
  unsigned char out;
  if (E <= 0) out = (unsigned char)rintf(m * 512.f);
  else        out = (unsigned char)((E << 3) | ((mb >> 20) & 7));
  return (unsigned char)(s | out);
#endif
}
// software decode bit-trick: result = e4m3(b) * 2^-120 (exact); caller folds 2^120.
__device__ __forceinline__ float fp8bits(unsigned int b){
  unsigned int t = ((b & 0x80u) << 24) | ((b & 0x7fu) << 20);
  float f; __builtin_memcpy(&f, &t, 4); return f;
}

// async global->LDS, 16B per lane
__device__ __forceinline__ void gl_lds16(const unsigned short* g, unsigned short* l){
  __builtin_amdgcn_global_load_lds(
      (const __attribute__((address_space(1))) unsigned int*)g,
      (__attribute__((address_space(3))) unsigned int*)l,
      16, 0, 0);
}

// ---------------- fused weight prep + zero-init (one launch) ----------------
__global__ __launch_bounds__(256) void k_prep(
    const float* __restrict__ W_in, const float* __restrict__ W_xproj,
    const float* __restrict__ W_dt, const float* __restrict__ W_out,
    const float* __restrict__ Wg,
    unsigned short* __restrict__ WinT, unsigned short* __restrict__ WxT,
    unsigned short* __restrict__ WdtT, unsigned short* __restrict__ WoutT,
    unsigned short* __restrict__ WgT,
    int* __restrict__ pos, int* __restrict__ degS, float* __restrict__ outv)
{
  int b = blockIdx.x;
  if (b >= 21888){
    int tid = threadIdx.x;
    if (b < 21920)       pos[(b-21888)*256 + tid] = 0;
    else if (b < 21984)  degS[(b-21920)*256 + tid] = 0;   // degS+degD contiguous 2*NN
    else { outv[tid] = 0.f; outv[256+tid] = 0.f; outv[512+tid] = 0.f; }
    return;
  }
  const float* in; unsigned short* out; int K, N, Kp; long base;
  if (b < 9216)      { in = W_in;    out = WinT;  K = 768;  N = 3072; Kp = 768;  base = 0; }
  else if (b < 9984) { in = W_xproj; out = WxT;   K = 1536; N = 80;   Kp = 1536; base = (long)9216*256; }
  else if (b < 10368){ in = W_dt;    out = WdtT;  K = 48;   N = 1536; Kp = 64;   base = (long)9984*256; }
  else if (b < 14976){ in = W_out;   out = WoutT; K = 1536; N = 768;  Kp = 1536; base = (long)10368*256; }
  else {
    int g = (b - 14976) / 2304;
    in = Wg + (size_t)g*768*768; out = WgT + (size_t)g*768*768;
    K = 768; N = 768; Kp = 768; base = (long)(14976 + g*2304)*256;
  }
  long off = (long)b*256 + threadIdx.x - base;
  int n = (int)(off / Kp), k = (int)(off % Kp);
  unsigned short v = 0;
  if (k < K && n < N) v = f2bf(in[(size_t)k*N + n]);
  out[off] = v;
}

// ---------------- rank + deg_count (merged) ----------------
__global__ __launch_bounds__(256) void k_rank_deg(const int* __restrict__ ts, int* __restrict__ pos,
                                                  const int* __restrict__ esrc, const int* __restrict__ edst,
                                                  int* __restrict__ degS, int* __restrict__ degD){
  int b = blockIdx.x;
  if (b < 1024){
    __shared__ int sT[256];
    int ic = b & 31, jc = b >> 5;
    int i = ic*256 + threadIdx.x;
    int my = ts[i];
    int c0 = jc*256;
    sT[threadIdx.x] = ts[c0 + threadIdx.x];
    __syncthreads();
    int r = 0;
    #pragma unroll 8
    for (int j = 0; j < 256; j++){
      int t = sT[j]; int jj = c0 + j;
      r += (t < my || (t == my && jj < i)) ? 1 : 0;
    }
    atomicAdd(&pos[i], r);
  } else {
    int e = (b-1024)*256 + threadIdx.x;
    atomicAdd(&degS[esrc[e]], 1); atomicAdd(&degD[edst[e]], 1);
  }
}

// ---------------- norms + rowptr (merged; 1024 threads) ----------------
__global__ __launch_bounds__(1024) void k_graphfix(const int* __restrict__ degS, const int* __restrict__ degD,
                                                   float* __restrict__ normS, float* __restrict__ normD,
                                                   int* __restrict__ row_ptr, int* __restrict__ cursor){
  int b = blockIdx.x;
  int tid = threadIdx.x;
  if (b < 8){
    int i = b*1024 + tid;
    normS[i] = rsqrtf(fmaxf((float)degS[i], 1.f));
    normD[i] = rsqrtf(fmaxf((float)degD[i], 1.f));
    return;
  }
  __shared__ int sp[1024];
  int base = tid*8;
  int loc[8]; int s = 0;
  #pragma unroll
  for (int j = 0; j < 8; j++){ loc[j] = degD[base+j]; s += loc[j]; }
  sp[tid] = s; __syncthreads();
  for (int o = 1; o < 1024; o <<= 1){
    int v = (tid >= o) ? sp[tid-o] : 0; __syncthreads();
    sp[tid] += v; __syncthreads();
  }
  int run = sp[tid] - s;
  #pragma unroll
  for (int j = 0; j < 8; j++){ row_ptr[base+j] = run; cursor[base+j] = run; run += loc[j]; }
  if (tid == 1023) row_ptr[NN] = sp[1023];
}

// ---------------- gather + csr_fill (merged) ----------------
__global__ __launch_bounds__(256) void k_scatter(const float* __restrict__ nf, const int* __restrict__ pos,
                                                 unsigned short* __restrict__ seq,
                                                 const int* __restrict__ esrc, const int* __restrict__ edst,
                                                 int* __restrict__ cursor, int* __restrict__ csr_src){
  int b = blockIdx.x;
  if (b < NN){
    int p = pos[b];
    const float* src = nf + (size_t)b*DF;
    unsigned short* dst = seq + (size_t)p*DF;
    for (int j = threadIdx.x; j < DF; j += 256) dst[j] = f2bf(src[j]);
  } else {
    int e = (b-NN)*256 + threadIdx.x;
    int d = edst[e];
    int p = atomicAdd(&cursor[d], 1);
    csr_src[p] = esrc[e];
  }
}

// ---------------- bf16 MFMA GEMM (128x128 tile, BK=64, 4 waves) ----------------
// XCD-chunked blockIdx swizzle (T1). EPI: 0 bf16; 1 f32+dt48; 2 softplus bf16;
// 3 gelu bf16; 4 gelu*normS fp8; 5 v*normS fp8
template<int EPI>
__global__ __launch_bounds__(256) void k_gemm(
    const unsigned short* __restrict__ A, const unsigned short* __restrict__ B,
    int N, int K, int lda, int ldb,
    float* __restrict__ outF, int ldoF,
    unsigned short* __restrict__ outB, int ldoB,
    const float* __restrict__ bias,
    unsigned short* __restrict__ out2,
    unsigned char* __restrict__ outQ,
    const float* __restrict__ nrmS)
{
  __shared__ unsigned short sA[2][128*32];
  __shared__ unsigned short sB[2][128*32];
  int tid = threadIdx.x;
  int tnc = N >> 7;
  int nwg = gridDim.x;
  int bid = blockIdx.x;
  int swz = (nwg & 7) ? bid : ((bid & 7)*(nwg >> 3) + (bid >> 3));
  int bm = (swz / tnc) << 7;
  int bn = (swz % tnc) << 7;
  int wv = tid >> 6, lane = tid & 63;
  int wm = wv >> 1, wn = wv & 1;
  int l15 = lane & 15, l4 = lane >> 4;

  f32x4 acc[4][4];
  #pragma unroll
  for (int i = 0; i < 4; i++)
    #pragma unroll
    for (int j = 0; j < 4; j++)
      acc[i][j] = (f32x4){0.f,0.f,0.f,0.f};

  int r0 = (wv*2)*16 + (lane >> 2);
  int r1 = r0 + 16;
  int cc = (lane & 3)*8;
  const unsigned short* gA0 = A + (size_t)(bm + r0)*lda + cc;
  const unsigned short* gA1 = A + (size_t)(bm + r1)*lda + cc;
  const unsigned short* gB0 = B + (size_t)(bn + r0)*ldb + cc;
  const unsigned short* gB1 = B + (size_t)(bn + r1)*ldb + cc;
  unsigned short* lA0 = &sA[0][(size_t)(wv*2)*512];
  unsigned short* lA1 = &sA[1][(size_t)(wv*2)*512];
  unsigned short* lB0 = &sB[0][(size_t)(wv*2)*512];
  unsigned short* lB1 = &sB[1][(size_t)(wv*2)*512];

  for (int k0 = 0; k0 < K; k0 += 64){
    __syncthreads();
    gl_lds16(gA0 + k0,      lA0);
    gl_lds16(gA1 + k0,      lA0 + 512);
    gl_lds16(gA0 + k0 + 32, lA1);
    gl_lds16(gA1 + k0 + 32, lA1 + 512);
    gl_lds16(gB0 + k0,      lB0);
    gl_lds16(gB1 + k0,      lB0 + 512);
    gl_lds16(gB0 + k0 + 32, lB1);
    gl_lds16(gB1 + k0 + 32, lB1 + 512);
    __syncthreads();
    #pragma unroll
    for (int h = 0; h < 2; h++){
      short8 af[4], bf_[4];
      #pragma unroll
      for (int i = 0; i < 4; i++){
        af[i]  = *(const short8*)&sA[h][(wm*64 + i*16 + l15)*32 + l4*8];
        bf_[i] = *(const short8*)&sB[h][(wn*64 + i*16 + l15)*32 + l4*8];
      }
      #pragma unroll
      for (int i = 0; i < 4; i++)
        #pragma unroll
        for (int j = 0; j < 4; j++)
          acc[i][j] = __builtin_amdgcn_mfma_f32_16x16x32_bf16(af[i], bf_[j], acc[i][j], 0, 0, 0);
    }
  }

  #pragma unroll
  for (int i = 0; i < 4; i++)
    #pragma unroll
    for (int j = 0; j < 4; j++)
      #pragma unroll
      for (int rr = 0; rr < 4; rr++){
        int row = bm + wm*64 + i*16 + l4*4 + rr;
        int col = bn + wn*64 + j*16 + l15;
        float v = acc[i][j][rr];
        if (EPI == 0){
          outB[(size_t)row*ldoB + col] = f2bf(v);
        } else if (EPI == 1){
          outF[(size_t)row*ldoF + col] = v;
          if (col < 64) out2[(size_t)row*64 + col] = (col < 48) ? f2bf(v) : (unsigned short)0;
        } else if (EPI == 2){
          outB[(size_t)row*ldoB + col] = f2bf(softplusf_(v + bias[col]));
        } else if (EPI == 3){
          v += bias[col];
          float g = 0.5f*v*(1.f + erff(v*0.70710678118f));
          outB[(size_t)row*ldoB + col] = f2bf(g);
        } else if (EPI == 4){
          v += bias[col];
          float g = 0.5f*v*(1.f + erff(v*0.70710678118f));
          outQ[(size_t)row*ldoB + col] = f2fp8(g * nrmS[row]);
        } else {
          outQ[(size_t)row*ldoB + col] = f2fp8(v * nrmS[row]);
        }
      }
}

// ---------------- causal conv + silu: sliding window, 8-wide load batch ----------------
__global__ __launch_bounds__(256) void k_conv_silu(const unsigned short* __restrict__ xz,
                                                   const float* __restrict__ conv_w,
                                                   const float* __restrict__ conv_b,
                                                   unsigned short* __restrict__ u){
  int c = blockIdx.x*256 + threadIdx.x;   // 0..1535
  int t0 = blockIdx.y*CT;
  float w0 = conv_w[c*4], w1 = conv_w[c*4+1], w2 = conv_w[c*4+2], w3 = conv_w[c*4+3];
  float bb = conv_b[c];
  const unsigned short* xp = xz + c;      // column base, row stride 3072
  float x0 = (t0 >= 3) ? bf2f(xp[(size_t)(t0-3)*3072]) : 0.f;
  float x1 = (t0 >= 2) ? bf2f(xp[(size_t)(t0-2)*3072]) : 0.f;
  float x2 = (t0 >= 1) ? bf2f(xp[(size_t)(t0-1)*3072]) : 0.f;
  unsigned short* up = u + (size_t)t0*DIM + c;
  for (int r0 = 0; r0 < CT; r0 += 8){
    unsigned short xb[8];
    #pragma unroll
    for (int j = 0; j < 8; j++) xb[j] = xp[(size_t)(t0+r0+j)*3072];
    #pragma unroll
    for (int j = 0; j < 8; j++){
      float x3 = bf2f(xb[j]);
      float acc = bb + x0*w0 + x1*w1 + x2*w2 + x3*w3;
      up[(r0+j)*DIM] = f2bf(acc * sigmoidf_(acc));
      x0 = x1; x1 = x2; x2 = x3;
    }
  }
}

// ---------------- selective scan: single sequential pass + parallel correction ----------------
__device__ __forceinline__ void pow_tree(float e1, float dA[16]){
  float e2 = e1*e1, e4 = e2*e2, e8 = e4*e4;
  dA[0]=e1;      dA[1]=e2;      dA[2]=e2*e1;   dA[3]=e4;
  dA[4]=e4*e1;   dA[5]=e4*e2;   dA[6]=e4*dA[2];dA[7]=e8;
  dA[8]=e8*e1;   dA[9]=e8*e2;   dA[10]=e8*dA[2];dA[11]=e8*e4;
  dA[12]=e8*dA[4];dA[13]=e8*dA[5];dA[14]=e8*dA[6];dA[15]=e8*e8;
}

// scanA': local recurrence + C-dot; stores pre-gate ylocal (bf16), hend, aprod
// fast path: 8-step register batch of dt/u loads (MLP depth 16 vs 2)
__global__ __launch_bounds__(256) void k_scanA(
    const unsigned short* __restrict__ delta, const unsigned short* __restrict__ u,
    const float* __restrict__ dbc, const float* __restrict__ A_log,
    const float* __restrict__ D_param,
    float* __restrict__ hend, float* __restrict__ aprod,
    unsigned short* __restrict__ ylocal)
{
  __shared__ float sBC[CL][32];
  int tid = threadIdx.x;
  int c = blockIdx.x*256 + tid;
  int k = blockIdx.y;
  float al2[16];
  #pragma unroll
  for (int s = 0; s < 16; s++) al2[s] = -expf(A_log[(size_t)c*16 + s]) * LOG2E;
  bool fast = true;
  #pragma unroll
  for (int s = 1; s < 16; s++)
    fast = fast && (fabsf(al2[s] - (float)(s+1)*al2[0]) <= 1e-4f*fabsf(al2[s]));
  float Dc = D_param[c];
  float h[16];
  #pragma unroll
  for (int s = 0; s < 16; s++) h[s] = 0.f;
  float sdt = 0.f;
  for (int idx = tid; idx < CL*32; idx += 256){
    int t = idx >> 5, j = idx & 31;
    sBC[t][j] = dbc[(size_t)(k*CL + t)*128 + 48 + j];
  }
  __syncthreads();
  const unsigned short* dp = delta + (size_t)k*CL*DIM + c;
  const unsigned short* up = u + (size_t)k*CL*DIM + c;
  unsigned short* yp = ylocal + (size_t)k*CL*DIM + c;
  if (fast){
    for (int t0 = 0; t0 < CL; t0 += 8){
      unsigned short dtb[8], uub[8];
      #pragma unroll
      for (int j = 0; j < 8; j++){
        dtb[j] = dp[(t0+j)*DIM];
        uub[j] = up[(t0+j)*DIM];
      }
      #pragma unroll
      for (int j = 0; j < 8; j++){
        int t = t0 + j;
        float dt = bf2f(dtb[j]), uu = bf2f(uub[j]);
        f32x4 Bv[4], Cv[4];
        #pragma unroll
        for (int q = 0; q < 4; q++){
          Bv[q] = *(const f32x4*)&sBC[t][q*4];
          Cv[q] = *(const f32x4*)&sBC[t][16 + q*4];
        }
        float dtu = dt*uu;
        sdt += dt;
        float dA[16];
        pow_tree(EXP2RAW(dt*al2[0]), dA);
        float ap[4] = {0.f,0.f,0.f,0.f};
        #pragma unroll
        for (int s = 0; s < 16; s++){
          h[s] = h[s]*dA[s] + dtu*Bv[s>>2][s&3];
          ap[s>>2] += h[s]*Cv[s>>2][s&3];
        }
        float accv = (ap[0]+ap[1]) + (ap[2]+ap[3]);
        yp[t*DIM] = f2bf(accv + uu*Dc);      // pre-gate local y
      }
    }
  } else {
    unsigned short dtn = dp[0], uun = up[0];
    #pragma unroll 2
    for (int t = 0; t < CL; t++){
      float dt = bf2f(dtn), uu = bf2f(uun);
      int tn = (t+1 < CL) ? t+1 : t;
      dtn = dp[tn*DIM]; uun = up[tn*DIM];
      f32x4 Bv[4], Cv[4];
      #pragma unroll
      for (int q = 0; q < 4; q++){
        Bv[q] = *(const f32x4*)&sBC[t][q*4];
        Cv[q] = *(const f32x4*)&sBC[t][16 + q*4];
      }
      float dtu = dt*uu;
      sdt += dt;
      float ap[4] = {0.f,0.f,0.f,0.f};
      #pragma unroll
      for (int s = 0; s < 16; s++){
        float dA = EXP2RAW(dt*al2[s]);
        h[s] = h[s]*dA + dtu*Bv[s>>2][s&3];
        ap[s>>2] += h[s]*Cv[s>>2][s&3];
      }
      float accv = (ap[0]+ap[1]) + (ap[2]+ap[3]);
      yp[t*DIM] = f2bf(accv + uu*Dc);
    }
  }
  size_t base = ((size_t)k*DIM + c)*16;
  #pragma unroll
  for (int s = 0; s < 16; s += 4){
    *(f32x4*)&hend[base+s]  = (f32x4){h[s],h[s+1],h[s+2],h[s+3]};
    *(f32x4*)&aprod[base+s] = (f32x4){EXP2RAW(al2[s]*sdt),EXP2RAW(al2[s+1]*sdt),
                                      EXP2RAW(al2[s+2]*sdt),EXP2RAW(al2[s+3]*sdt)};
  }
}

// scanB: 8-deep load prefetch. Addresses are k-deterministic; reads of a batch
// all precede its writes (original order already had read[k] before write[k]),
// so batching reads is bit-identical.
__global__ __launch_bounds__(256) void k_scanB(float* __restrict__ hend, const float* __restrict__ aprod){
  int i = blockIdx.x*256 + threadIdx.x;
  float H = 0.f;
  for (int k0 = 0; k0 < NCH; k0 += 8){
    float e[8], ap[8];
    #pragma unroll
    for (int j = 0; j < 8; j++){
      size_t o = (size_t)(k0+j)*DIM*16 + i;
      e[j] = hend[o]; ap[j] = aprod[o];
    }
    #pragma unroll
    for (int j = 0; j < 8; j++){
      size_t o = (size_t)(k0+j)*DIM*16 + i;
      hend[o] = H;
      H = e[j] + ap[j]*H;
    }
  }
}

// scanCorr: y[t] = (ylocal[t] + sum_s C[t][s]*Hin[s]*2^(al2[s]*cumdt[t])) * silu(z[t])
// Early-exit once 2^(alSlow*cum) < 2^-33; gate-only tail. 8-step register batching.
__global__ __launch_bounds__(256) void k_scanCorr(
    const unsigned short* __restrict__ delta, const unsigned short* __restrict__ xz,
    const float* __restrict__ dbc, const float* __restrict__ A_log,
    const float* __restrict__ hin, unsigned short* __restrict__ y)
{
  __shared__ float sC[CL][16];
  int tid = threadIdx.x;
  int c = blockIdx.x*256 + tid;
  int k = blockIdx.y;
  float al2[16];
  #pragma unroll
  for (int s = 0; s < 16; s++) al2[s] = -expf(A_log[(size_t)c*16 + s]) * LOG2E;
  bool fast = true;
  #pragma unroll
  for (int s = 1; s < 16; s++)
    fast = fast && (fabsf(al2[s] - (float)(s+1)*al2[0]) <= 1e-4f*fabsf(al2[s]));
  float alSlow = al2[0];
  #pragma unroll
  for (int s = 1; s < 16; s++) alSlow = fmaxf(alSlow, al2[s]);
  float Hin[16];
  size_t base = ((size_t)k*DIM + c)*16;
  #pragma unroll
  for (int s = 0; s < 16; s += 4){
    f32x4 v = *(const f32x4*)&hin[base+s];
    Hin[s] = v.x; Hin[s+1] = v.y; Hin[s+2] = v.z; Hin[s+3] = v.w;
  }
  for (int idx = tid; idx < CL*16; idx += 256){
    int t = idx >> 4, j = idx & 15;
    sC[t][j] = dbc[(size_t)(k*CL + t)*128 + 64 + j];
  }
  __syncthreads();
  const unsigned short* dp = delta + (size_t)k*CL*DIM + c;
  const unsigned short* zp = xz + (size_t)k*CL*3072 + 1536 + c;
  unsigned short* yp = y + (size_t)k*CL*DIM + c;
  float cum = 0.f;
  int t = 0;
  if (fast){
    bool done = false;
    for (int t0 = 0; t0 < CL && !done; t0 += 8){
      unsigned short dtb[8], zzb[8], ylb[8];
      #pragma unroll
      for (int j = 0; j < 8; j++){
        dtb[j] = dp[(t0+j)*DIM];
        zzb[j] = zp[(t0+j)*3072];
        ylb[j] = yp[(t0+j)*DIM];
      }
      #pragma unroll
      for (int j = 0; j < 8; j++){
        float dt = bf2f(dtb[j]);
        cum += dt;
        float e1 = EXP2RAW(cum*al2[0]);
        if (e1 < 0x1p-33f){ t = t0 + j; done = true; break; }
        float dA[16];
        pow_tree(e1, dA);
        f32x4 Cv[4];
        #pragma unroll
        for (int q = 0; q < 4; q++) Cv[q] = *(const f32x4*)&sC[t0+j][q*4];
        float ap[4] = {0.f,0.f,0.f,0.f};
        #pragma unroll
        for (int s = 0; s < 16; s++)
          ap[s>>2] += Hin[s]*dA[s]*Cv[s>>2][s&3];
        float corr = (ap[0]+ap[1]) + (ap[2]+ap[3]);
        float yl = bf2f(ylb[j]);
        float zz = bf2f(zzb[j]);
        yp[(t0+j)*DIM] = f2bf((yl + corr) * (zz * sigmoidf_(zz)));
      }
      if (!done) t = t0 + 8;
    }
  } else {
    for (; t < CL; t++){
      float dt = bf2f(dp[t*DIM]);
      cum += dt;
      if (EXP2RAW(cum*alSlow) < 0x1p-33f) break;
      f32x4 Cv[4];
      #pragma unroll
      for (int q = 0; q < 4; q++) Cv[q] = *(const f32x4*)&sC[t][q*4];
      float ap[4] = {0.f,0.f,0.f,0.f};
      #pragma unroll
      for (int s = 0; s < 16; s++)
        ap[s>>2] += Hin[s]*EXP2RAW(cum*al2[s])*Cv[s>>2][s&3];
      float corr = (ap[0]+ap[1]) + (ap[2]+ap[3]);
      float yl = bf2f(yp[t*DIM]);
      float zz = bf2f(zp[t*3072]);
      float yv = (yl + corr) * (zz * sigmoidf_(zz));
      yp[t*DIM] = f2bf(yv);
    }
  }
  // gate-only tail (batched)
  for (; t + 7 < CL; t += 8){
    unsigned short zzb[8], ylb[8];
    #pragma unroll
    for (int j = 0; j < 8; j++){
      ylb[j] = yp[(t+j)*DIM];
      zzb[j] = zp[(t+j)*3072];
    }
    #pragma unroll
    for (int j = 0; j < 8; j++){
      float yl = bf2f(ylb[j]);
      float zz = bf2f(zzb[j]);
      yp[(t+j)*DIM] = f2bf(yl * (zz * sigmoidf_(zz)));
    }
  }
  for (; t < CL; t++){
    float yl = bf2f(yp[t*DIM]);
    float zz = bf2f(zp[t*3072]);
    yp[t*DIM] = f2bf(yl * (zz * sigmoidf_(zz)));
  }
}

// ---------------- GCN aggregation (fp8 rows; HW cvt decode, 8-edge MLP unroll) ----------------
// Accumulation kept as two sequential quad-adds -> bit-identical to 4-edge version.
__global__ __launch_bounds__(192) void k_aggregate(
    const unsigned char* __restrict__ hq, const int* __restrict__ row_ptr,
    const int* __restrict__ csr_src, const float* __restrict__ normD,
    unsigned short* __restrict__ m)
{
  int d = blockIdx.x; int tid = threadIdx.x;
  int e0 = row_ptr[d], e1 = row_ptr[d+1];
  float a0 = 0.f, a1 = 0.f, a2 = 0.f, a3 = 0.f;
#if __has_builtin(__builtin_amdgcn_cvt_f32_fp8)
  int e = e0;
  for (; e + 7 < e1; e += 8){
    int sx[8];
    #pragma unroll
    for (int j = 0; j < 8; j++) sx[j] = csr_src[e+j];
    unsigned int w[8];
    #pragma unroll
    for (int j = 0; j < 8; j++) w[j] = *((const unsigned int*)(hq + (size_t)sx[j]*DF) + tid);
    a0 += (__builtin_amdgcn_cvt_f32_fp8(w[0], 0) + __builtin_amdgcn_cvt_f32_fp8(w[1], 0))
        + (__builtin_amdgcn_cvt_f32_fp8(w[2], 0) + __builtin_amdgcn_cvt_f32_fp8(w[3], 0));
    a1 += (__builtin_amdgcn_cvt_f32_fp8(w[0], 1) + __builtin_amdgcn_cvt_f32_fp8(w[1], 1))
        + (__builtin_amdgcn_cvt_f32_fp8(w[2], 1) + __builtin_amdgcn_cvt_f32_fp8(w[3], 1));
    a2 += (__builtin_amdgcn_cvt_f32_fp8(w[0], 2) + __builtin_amdgcn_cvt_f32_fp8(w[1], 2))
        + (__builtin_amdgcn_cvt_f32_fp8(w[2], 2) + __builtin_amdgcn_cvt_f32_fp8(w[3], 2));
    a3 += (__builtin_amdgcn_cvt_f32_fp8(w[0], 3) + __builtin_amdgcn_cvt_f32_fp8(w[1], 3))
        + (__builtin_amdgcn_cvt_f32_fp8(w[2], 3) + __builtin_amdgcn_cvt_f32_fp8(w[3], 3));
    a0 += (__builtin_amdgcn_cvt_f32_fp8(w[4], 0) + __builtin_amdgcn_cvt_f32_fp8(w[5], 0))
        + (__builtin_amdgcn_cvt_f32_fp8(w[6], 0) + __builtin_amdgcn_cvt_f32_fp8(w[7], 0));
    a1 += (__builtin_amdgcn_cvt_f32_fp8(w[4], 1) + __builtin_amdgcn_cvt_f32_fp8(w[5], 1))
        + (__builtin_amdgcn_cvt_f32_fp8(w[6], 1) + __builtin_amdgcn_cvt_f32_fp8(w[7], 1));
    a2 += (__builtin_amdgcn_cvt_f32_fp8(w[4], 2) + __builtin_amdgcn_cvt_f32_fp8(w[5], 2))
        + (__builtin_amdgcn_cvt_f32_fp8(w[6], 2) + __builtin_amdgcn_cvt_f32_fp8(w[7], 2));
    a3 += (__builtin_amdgcn_cvt_f32_fp8(w[4], 3) + __builtin_amdgcn_cvt_f32_fp8(w[5], 3))
        + (__builtin_amdgcn_cvt_f32_fp8(w[6], 3) + __builtin_amdgcn_cvt_f32_fp8(w[7], 3));
  }
  for (; e + 3 < e1; e += 4){
    int s0 = csr_src[e],   s1 = csr_src[e+1];
    int s2 = csr_src[e+2], s3 = csr_src[e+3];
    unsigned int w0 = *((const unsigned int*)(hq + (size_t)s0*DF) + tid);
    unsigned int w1 = *((const unsigned int*)(hq + (size_t)s1*DF) + tid);
    unsigned int w2 = *((const unsigned int*)(hq + (size_t)s2*DF) + tid);
    unsigned int w3 = *((const unsigned int*)(hq + (size_t)s3*DF) + tid);
    a0 += (__builtin_amdgcn_cvt_f32_fp8(w0, 0) + __builtin_amdgcn_cvt_f32_fp8(w1, 0))
        + (__builtin_amdgcn_cvt_f32_fp8(w2, 0) + __builtin_amdgcn_cvt_f32_fp8(w3, 0));
    a1 += (__builtin_amdgcn_cvt_f32_fp8(w0, 1) + __builtin_amdgcn_cvt_f32_fp8(w1, 1))
        + (__builtin_amdgcn_cvt_f32_fp8(w2, 1) + __builtin_amdgcn_cvt_f32_fp8(w3, 1));
    a2 += (__builtin_amdgcn_cvt_f32_fp8(w0, 2) + __builtin_amdgcn_cvt_f32_fp8(w1, 2))
        + (__builtin_amdgcn_cvt_f32_fp8(w2, 2) + __builtin_amdgcn_cvt_f32_fp8(w3, 2));
    a3 += (__builtin_amdgcn_cvt_f32_fp8(w0, 3) + __builtin_amdgcn_cvt_f32_fp8(w1, 3))
        + (__builtin_amdgcn_cvt_f32_fp8(w2, 3) + __builtin_amdgcn_cvt_f32_fp8(w3, 3));
  }
  for (; e < e1; e++){
    int s0 = csr_src[e];
    unsigned int w0 = *((const unsigned int*)(hq + (size_t)s0*DF) + tid);
    a0 += __builtin_amdgcn_cvt_f32_fp8(w0, 0);
    a1 += __builtin_amdgcn_cvt_f32_fp8(w0, 1);
    a2 += __builtin_amdgcn_cvt_f32_fp8(w0, 2);
    a3 += __builtin_amdgcn_cvt_f32_fp8(w0, 3);
  }
  float nd = normD[d] * (1.f/H8SCALE);   // HW decode yields true e4m3 value
#else
  for (int e = e0; e < e1; e++){
    int sI = csr_src[e];
    unsigned int w = *((const unsigned int*)(hq + (size_t)sI*DF) + tid);
    a0 += fp8bits(w & 255u);
    a1 += fp8bits((w >> 8) & 255u);
    a2 += fp8bits((w >> 16) & 255u);
    a3 += fp8bits(w >> 24);
  }
  float nd = normD[d] * 0x1p+114f;       // 2^120 decode scale / H8SCALE(=2^6)
#endif
  uint2 o;
  o.x = (unsigned int)f2bf(a0*nd) | ((unsigned int)f2bf(a1*nd) << 16);
  o.y = (unsigned int)f2bf(a2*nd) | ((unsigned int)f2bf(a3*nd) << 16);
  *((uint2*)(m + (size_t)d*DF) + tid) = o;
}

// ---------------- finals (causal + gfeat merged; gfeat 768 blocks x 32 rows) ----------------
__global__ __launch_bounds__(256) void k_final(const unsigned short* __restrict__ h,
                                               const float* __restrict__ W_c,
                                               const float* __restrict__ b_c,
                                               float* __restrict__ out){
  int b = blockIdx.x;
  if (b < 2048){
    int wv = threadIdx.x >> 6, lane = threadIdx.x & 63;
    int r = b*4 + wv;
    float s = 0.f;
    #pragma unroll
    for (int j = 0; j < 12; j++){
      int cidx = lane + 64*j;
      s += bf2f(h[(size_t)r*DF + cidx]) * W_c[cidx];
    }
    s += __shfl_xor(s, 32); s += __shfl_xor(s, 16); s += __shfl_xor(s, 8);
    s += __shfl_xor(s, 4);  s += __shfl_xor(s, 2);  s += __shfl_xor(s, 1);
    if (lane == 0){
      float a = s + b_c[0];
      float cz = 1.f/(1.f + expf(-a));   // precise libm for f32 output
      out[DF + r] = cz;
      out[DF + NN + r] = (cz > 0.7f) ? 1.f : 0.f;
    }
  } else {
    int g = b - 2048;                 // 0..767
    int col = (g % 3)*256 + threadIdx.x;
    int r0 = (g / 3)*32;              // 256 chunks x 32 rows
    float s = 0.f;
    #pragma unroll 4
    for (int r = r0; r < r0 + 32; r++) s += bf2f(h[(size_t)r*DF + col]);
    atomicAdd(&out[col], s * (1.f/8192.f));
  }
}

// ---------------- launch ----------------
extern "C" void kernel_launch(void* const* d_in, const int* in_sizes, int n_in,
                              void* d_out, int out_size, void* d_ws, size_t ws_size,
                              hipStream_t stream) {
  const float* node_feats = (const float*)d_in[0];
  const int*   timestamps = (const int*)d_in[1];
  const int*   ei         = (const int*)d_in[2];
  const int*   e_src = ei;
  const int*   e_dst = ei + NE_;
  const float* W_in    = (const float*)d_in[3];
  const float* conv_w  = (const float*)d_in[4];
  const float* conv_b  = (const float*)d_in[5];
  const float* W_xproj = (const float*)d_in[6];
  const float* W_dt    = (const float*)d_in[7];
  const float* b_dt    = (const float*)d_in[8];
  const float* A_log   = (const float*)d_in[9];
  const float* D_param = (const float*)d_in[10];
  const float* W_out   = (const float*)d_in[11];
  const float* Wg      = (const float*)d_in[12];
  const float* bg      = (const float*)d_in[13];
  const float* W_c     = (const float*)d_in[14];
  const float* b_c     = (const float*)d_in[15];
  float* out = (float*)d_out;

  char* ws = (char*)d_ws;
  size_t off = 0;
  auto alloc = [&](size_t bytes) -> char* {
    char* p = ws + off; off += (bytes + 255) & ~(size_t)255; return p;
  };
  unsigned short* WinT   = (unsigned short*)alloc((size_t)3072*768*2);
  unsigned short* WxT    = (unsigned short*)alloc((size_t)128*1536*2);
  unsigned short* WdtT   = (unsigned short*)alloc((size_t)1536*64*2);
  unsigned short* WoutT  = (unsigned short*)alloc((size_t)768*1536*2);
  unsigned short* WgT    = (unsigned short*)alloc((size_t)3*768*768*2);
  unsigned short* seq    = (unsigned short*)alloc((size_t)NN*DF*2);
  unsigned short* xz     = (unsigned short*)alloc((size_t)NN*3072*2);
  unsigned short* ubuf   = (unsigned short*)alloc((size_t)NN*DIM*2);
  float*          dbc    = (float*)alloc((size_t)NN*128*4);
  unsigned short* dt48   = (unsigned short*)alloc((size_t)NN*64*2);
  unsigned short* deltaB = (unsigned short*)alloc((size_t)NN*DIM*2);
  unsigned short* ybuf   = (unsigned short*)alloc((size_t)NN*DIM*2);
  unsigned short* hbuf   = (unsigned short*)alloc((size_t)NN*DF*2);
  unsigned short* mbuf   = (unsigned short*)alloc((size_t)NN*DF*2);
  unsigned char*  hq     = (unsigned char*)alloc((size_t)NN*DF);
  int*   pos    = (int*)alloc((size_t)NN*4);
  int*   degS   = (int*)alloc((size_t)2*NN*4);
  int*   degD   = degS + NN;
  float* normS  = (float*)alloc((size_t)NN*4);
  float* normD  = (float*)alloc((size_t)NN*4);
  int*   rowp   = (int*)alloc((size_t)(NN+1)*4);
  int*   cursor = (int*)alloc((size_t)NN*4);
  int*   csr    = (int*)alloc((size_t)NE_*4);

  // scan summaries: hend aliases seq (dead after G1); aprod aliases mbuf
  // (first written by k_aggregate, after scanB consumed aprod)
  float* hend  = (float*)seq;
  float* aprod = (float*)mbuf;

  // 1. weight prep + zero-init (pos/degS+degD/out[0:768])
  k_prep<<<21985, 256, 0, stream>>>(W_in, W_xproj, W_dt, W_out, Wg,
                                    WinT, WxT, WdtT, WoutT, WgT,
                                    pos, degS, out);
  // 2. rank + degree count
  k_rank_deg<<<2048, 256, 0, stream>>>(timestamps, pos, e_src, e_dst, degS, degD);
  // 3. norms + rowptr
  k_graphfix<<<9, 1024, 0, stream>>>(degS, degD, normS, normD, rowp, cursor);
  // 4. gather + csr fill
  k_scatter<<<NN + 1024, 256, 0, stream>>>(node_feats, pos, seq, e_src, e_dst, cursor, csr);

  // G1: xz = seq @ W_in
  k_gemm<0><<<64*24, 256, 0, stream>>>(seq, WinT, 3072, 768, 768, 768,
                                       nullptr, 0, xz, 3072, nullptr, nullptr, nullptr, nullptr);
  // conv + silu -> u (sliding-window, 8-wide load batch)
  k_conv_silu<<<dim3(6, NN/CT), 256, 0, stream>>>(xz, conv_w, conv_b, ubuf);
  // G2: dbc = u @ W_xproj; also dt48
  k_gemm<1><<<64*1, 256, 0, stream>>>(ubuf, WxT, 128, 1536, 1536, 1536,
                                      dbc, 128, nullptr, 0, nullptr, dt48, nullptr, nullptr);
  // G3: delta = softplus(...) -> bf16
  k_gemm<2><<<64*12, 256, 0, stream>>>(dt48, WdtT, 1536, 64, 64, 64,
                                       nullptr, 0, deltaB, 1536, b_dt, nullptr, nullptr, nullptr);
  // scan: single sequential pass + combine + parallel correction
  k_scanA<<<dim3(DIM/256, NCH), 256, 0, stream>>>(deltaB, ubuf, dbc, A_log, D_param, hend, aprod, ybuf);
  k_scanB<<<96, 256, 0, stream>>>(hend, aprod);
  k_scanCorr<<<dim3(DIM/256, NCH), 256, 0, stream>>>(deltaB, xz, dbc, A_log, hend, ybuf);
  // G4: h = y @ W_out -> fp8 (normS-prescaled)
  k_gemm<5><<<64*6, 256, 0, stream>>>(ybuf, WoutT, 768, 1536, 1536, 1536,
                                      nullptr, 0, nullptr, 768, nullptr, nullptr, hq, normS);
  // 3 GCN layers
  k_aggregate<<<NN, 192, 0, stream>>>(hq, rowp, csr, normD, mbuf);
  k_gemm<4><<<64*6, 256, 0, stream>>>(mbuf, WgT, 768, 768, 768, 768,
                                      nullptr, 0, nullptr, 768, bg, nullptr, hq, normS);
  k_aggregate<<<NN, 192, 0, stream>>>(hq, rowp, csr, normD, mbuf);
  k_gemm<4><<<64*6, 256, 0, stream>>>(mbuf, WgT + (size_t)768*768, 768, 768, 768, 768,
                                      nullptr, 0, nullptr, 768, bg + 768, nullptr, hq, normS);
  k_aggregate<<<NN, 192, 0, stream>>>(hq, rowp, csr, normD, mbuf);
  k_gemm<3><<<64*6, 256, 0, stream>>>(mbuf, WgT + (size_t)2*768*768, 768, 768, 768, 768,
                                      nullptr, 0, hbuf, 768, bg + 2*768, nullptr, nullptr, nullptr);
  // finals (causal + graph_feat)
  k_final<<<2816, 256, 0, stream>>>(hbuf, W_c, b_c, out);
}

// Round 35
// 455.829 us; speedup vs baseline: 1.0372x; 1.0372x over previous
//
#include <hip/hip_runtime.h>
#include <math.h>

#define NN 8192
#define DF 768
#define NE_ 262144
#define DIM 1536
#define DSN 16
#define NCH 128
#define CL  64   // NN / NCH
#define CT  64   // conv time-block

typedef short short8 __attribute__((ext_vector_type(8)));
typedef float f32x4 __attribute__((ext_vector_type(4)));

__device__ __forceinline__ float bf2f(unsigned short u){
  unsigned int v = ((unsigned int)u) << 16; float f; __builtin_memcpy(&f, &v, 4); return f;
}
__device__ __forceinline__ unsigned short f2bf(float f){
  unsigned int x; __builtin_memcpy(&x, &f, 4);
  x += 0x7fffu + ((x >> 16) & 1u);
  return (unsigned short)(x >> 16);
}
#define EXP2RAW(x) __builtin_amdgcn_exp2f(x)   // single v_exp_f32
#define LOG2E 1.44269504088896f
#define LN2   0.69314718055995f
#define H8SCALE 64.f
// fast sigmoid: native exp2 + rcp
__device__ __forceinline__ float sigmoidf_(float x){
  return 1.f/(1.f + EXP2RAW(-x*LOG2E));
}
// fast softplus: ln2 * log2(1 + 2^(v*log2e)); exact passthrough for large v
__device__ __forceinline__ float softplusf_(float v){
  if (v > 20.f) return v;
  return LN2 * __log2f(1.f + EXP2RAW(v*LOG2E));
}

// ---- fp8 e4m3fn encode ----
__device__ __forceinline__ unsigned char f2fp8(float v){
  float y = v * H8SCALE;
#if __has_builtin(__builtin_amdgcn_cvt_pk_fp8_f32)
  return (unsigned char)(__builtin_amdgcn_cvt_pk_fp8_f32(y, y, 0, false) & 0xff);
#else
  unsigned int u; __builtin_memcpy(&u, &y, 4);
  unsigned char s = (unsigned char)((u >> 24) & 0x80);
  float a = fabsf(y);
  if (a >= 448.f) return (unsigned char)(s | 0x7E);
  if (a < 0x1p-10f) return s;
  unsigned int ab = u & 0x7fffffffu;
  int ef = (int)(ab >> 23) - 127;
  int qe = ef - 3; if (qe < -9) qe = -9;
  float q; { unsigned int qb = (unsigned int)(qe + 127) << 23; __builtin_memcpy(&q, &qb, 4); }
  float n = rintf(a / q);
  float m = n * q;
  unsigned int mb; __builtin_memcpy(&mb, &m, 4);
  int E = (int)(mb >> 23) - 127 + 7;
  unsigned char out;
  if (E <= 0) out = (unsigned char)rintf(m * 512.f);
  else        out = (unsigned char)((E << 3) | ((mb >> 20) & 7));
  return (unsigned char)(s | out);
#endif
}
// software decode bit-trick: result = e4m3(b) * 2^-120 (exact); caller folds 2^120.
__device__ __forceinline__ float fp8bits(unsigned int b){
  unsigned int t = ((b & 0x80u) << 24) | ((b & 0x7fu) << 20);
  float f; __builtin_memcpy(&f, &t, 4); return f;
}

// async global->LDS, 16B per lane
__device__ __forceinline__ void gl_lds16(const unsigned short* g, unsigned short* l){
  __builtin_amdgcn_global_load_lds(
      (const __attribute__((address_space(1))) unsigned int*)g,
      (__attribute__((address_space(3))) unsigned int*)l,
      16, 0, 0);
}

// ---------------- weight prep: LDS-tiled transpose (coalesced both sides) ----------------
// 64x64 tiles; pitch 65 kills bank conflicts. Output element = f2bf(in[k*N+n]) --
// bit-identical to the old per-element path, including zero padding.
__global__ __launch_bounds__(256) void k_prep(
    const float* __restrict__ W_in, const float* __restrict__ W_xproj,
    const float* __restrict__ W_dt, const float* __restrict__ W_out,
    const float* __restrict__ Wg,
    unsigned short* __restrict__ WinT, unsigned short* __restrict__ WxT,
    unsigned short* __restrict__ WdtT, unsigned short* __restrict__ WoutT,
    unsigned short* __restrict__ WgT,
    int* __restrict__ pos, int* __restrict__ degS, float* __restrict__ outv)
{
  int b = blockIdx.x;
  int tid = threadIdx.x;
  if (b >= 1368){
    if (b < 1400)       pos[(b-1368)*256 + tid] = 0;
    else if (b < 1464)  degS[(b-1400)*256 + tid] = 0;   // degS+degD contiguous 2*NN
    else { outv[tid] = 0.f; outv[256+tid] = 0.f; outv[512+tid] = 0.f; }
    return;
  }
  // decode matrix + tile
  const float* in; unsigned short* out; int K, N, Kp, Np, kt, nt;
  if (b < 576){        in = W_in;    out = WinT;  K = 768;  N = 3072; Kp = 768;  Np = 3072;
                       kt = b / 48;  nt = b % 48; }
  else if (b < 624){   int l = b - 576;
                       in = W_xproj; out = WxT;   K = 1536; N = 80;   Kp = 1536; Np = 128;
                       kt = l >> 1;  nt = l & 1; }
  else if (b < 648){   int l = b - 624;
                       in = W_dt;    out = WdtT;  K = 48;   N = 1536; Kp = 64;   Np = 1536;
                       kt = 0;       nt = l; }
  else if (b < 936){   int l = b - 648;
                       in = W_out;   out = WoutT; K = 1536; N = 768;  Kp = 1536; Np = 768;
                       kt = l / 12;  nt = l % 12; }
  else {               int l = b - 936;
                       int g = l / 144; int r = l % 144;
                       in = Wg + (size_t)g*768*768; out = WgT + (size_t)g*768*768;
                       K = 768; N = 768; Kp = 768; Np = 768;
                       kt = r / 12;  nt = r % 12; }
  int k0 = kt*64, n0 = nt*64;
  __shared__ float tl[64][65];
  int ln = tid & 63;   // inner (contiguous) index
  int lk = tid >> 6;   // 0..3
  #pragma unroll
  for (int kk = lk; kk < 64; kk += 4){
    int gk = k0 + kk, gn = n0 + ln;
    float v = (gk < K && gn < N) ? in[(size_t)gk*N + gn] : 0.f;
    tl[kk][ln] = v;
  }
  __syncthreads();
  #pragma unroll
  for (int nn = lk; nn < 64; nn += 4){
    int gn2 = n0 + nn, gk2 = k0 + ln;
    if (gn2 < Np && gk2 < Kp)
      out[(size_t)gn2*Kp + gk2] = f2bf(tl[ln][nn]);
  }
}

// ---------------- rank + deg_count (merged) ----------------
__global__ __launch_bounds__(256) void k_rank_deg(const int* __restrict__ ts, int* __restrict__ pos,
                                                  const int* __restrict__ esrc, const int* __restrict__ edst,
                                                  int* __restrict__ degS, int* __restrict__ degD){
  int b = blockIdx.x;
  if (b < 1024){
    __shared__ int sT[256];
    int ic = b & 31, jc = b >> 5;
    int i = ic*256 + threadIdx.x;
    int my = ts[i];
    int c0 = jc*256;
    sT[threadIdx.x] = ts[c0 + threadIdx.x];
    __syncthreads();
    int r = 0;
    #pragma unroll 8
    for (int j = 0; j < 256; j++){
      int t = sT[j]; int jj = c0 + j;
      r += (t < my || (t == my && jj < i)) ? 1 : 0;
    }
    atomicAdd(&pos[i], r);
  } else {
    int e = (b-1024)*256 + threadIdx.x;
    atomicAdd(&degS[esrc[e]], 1); atomicAdd(&degD[edst[e]], 1);
  }
}

// ---------------- norms + rowptr (merged; 1024 threads) ----------------
__global__ __launch_bounds__(1024) void k_graphfix(const int* __restrict__ degS, const int* __restrict__ degD,
                                                   float* __restrict__ normS, float* __restrict__ normD,
                                                   int* __restrict__ row_ptr, int* __restrict__ cursor){
  int b = blockIdx.x;
  int tid = threadIdx.x;
  if (b < 8){
    int i = b*1024 + tid;
    normS[i] = rsqrtf(fmaxf((float)degS[i], 1.f));
    normD[i] = rsqrtf(fmaxf((float)degD[i], 1.f));
    return;
  }
  __shared__ int sp[1024];
  int base = tid*8;
  int loc[8]; int s = 0;
  #pragma unroll
  for (int j = 0; j < 8; j++){ loc[j] = degD[base+j]; s += loc[j]; }
  sp[tid] = s; __syncthreads();
  for (int o = 1; o < 1024; o <<= 1){
    int v = (tid >= o) ? sp[tid-o] : 0; __syncthreads();
    sp[tid] += v; __syncthreads();
  }
  int run = sp[tid] - s;
  #pragma unroll
  for (int j = 0; j < 8; j++){ row_ptr[base+j] = run; cursor[base+j] = run; run += loc[j]; }
  if (tid == 1023) row_ptr[NN] = sp[1023];
}

// ---------------- gather + csr_fill (merged) ----------------
__global__ __launch_bounds__(256) void k_scatter(const float* __restrict__ nf, const int* __restrict__ pos,
                                                 unsigned short* __restrict__ seq,
                                                 const int* __restrict__ esrc, const int* __restrict__ edst,
                                                 int* __restrict__ cursor, int* __restrict__ csr_src){
  int b = blockIdx.x;
  if (b < NN){
    int p = pos[b];
    const float* src = nf + (size_t)b*DF;
    unsigned short* dst = seq + (size_t)p*DF;
    for (int j = threadIdx.x; j < DF; j += 256) dst[j] = f2bf(src[j]);
  } else {
    int e = (b-NN)*256 + threadIdx.x;
    int d = edst[e];
    int p = atomicAdd(&cursor[d], 1);
    csr_src[p] = esrc[e];
  }
}

// ---------------- bf16 MFMA GEMM (128x128 tile, BK=64, 4 waves) ----------------
// XCD-chunked blockIdx swizzle (T1). EPI: 0 bf16; 1 f32+dt48; 2 softplus bf16;
// 3 gelu bf16; 4 gelu*normS fp8; 5 v*normS fp8
template<int EPI>
__global__ __launch_bounds__(256) void k_gemm(
    const unsigned short* __restrict__ A, const unsigned short* __restrict__ B,
    int N, int K, int lda, int ldb,
    float* __restrict__ outF, int ldoF,
    unsigned short* __restrict__ outB, int ldoB,
    const float* __restrict__ bias,
    unsigned short* __restrict__ out2,
    unsigned char* __restrict__ outQ,
    const float* __restrict__ nrmS)
{
  __shared__ unsigned short sA[2][128*32];
  __shared__ unsigned short sB[2][128*32];
  int tid = threadIdx.x;
  int tnc = N >> 7;
  int nwg = gridDim.x;
  int bid = blockIdx.x;
  int swz = (nwg & 7) ? bid : ((bid & 7)*(nwg >> 3) + (bid >> 3));
  int bm = (swz / tnc) << 7;
  int bn = (swz % tnc) << 7;
  int wv = tid >> 6, lane = tid & 63;
  int wm = wv >> 1, wn = wv & 1;
  int l15 = lane & 15, l4 = lane >> 4;

  f32x4 acc[4][4];
  #pragma unroll
  for (int i = 0; i < 4; i++)
    #pragma unroll
    for (int j = 0; j < 4; j++)
      acc[i][j] = (f32x4){0.f,0.f,0.f,0.f};

  int r0 = (wv*2)*16 + (lane >> 2);
  int r1 = r0 + 16;
  int cc = (lane & 3)*8;
  const unsigned short* gA0 = A + (size_t)(bm + r0)*lda + cc;
  const unsigned short* gA1 = A + (size_t)(bm + r1)*lda + cc;
  const unsigned short* gB0 = B + (size_t)(bn + r0)*ldb + cc;
  const unsigned short* gB1 = B + (size_t)(bn + r1)*ldb + cc;
  unsigned short* lA0 = &sA[0][(size_t)(wv*2)*512];
  unsigned short* lA1 = &sA[1][(size_t)(wv*2)*512];
  unsigned short* lB0 = &sB[0][(size_t)(wv*2)*512];
  unsigned short* lB1 = &sB[1][(size_t)(wv*2)*512];

  for (int k0 = 0; k0 < K; k0 += 64){
    __syncthreads();
    gl_lds16(gA0 + k0,      lA0);
    gl_lds16(gA1 + k0,      lA0 + 512);
    gl_lds16(gA0 + k0 + 32, lA1);
    gl_lds16(gA1 + k0 + 32, lA1 + 512);
    gl_lds16(gB0 + k0,      lB0);
    gl_lds16(gB1 + k0,      lB0 + 512);
    gl_lds16(gB0 + k0 + 32, lB1);
    gl_lds16(gB1 + k0 + 32, lB1 + 512);
    __syncthreads();
    #pragma unroll
    for (int h = 0; h < 2; h++){
      short8 af[4], bf_[4];
      #pragma unroll
      for (int i = 0; i < 4; i++){
        af[i]  = *(const short8*)&sA[h][(wm*64 + i*16 + l15)*32 + l4*8];
        bf_[i] = *(const short8*)&sB[h][(wn*64 + i*16 + l15)*32 + l4*8];
      }
      #pragma unroll
      for (int i = 0; i < 4; i++)
        #pragma unroll
        for (int j = 0; j < 4; j++)
          acc[i][j] = __builtin_amdgcn_mfma_f32_16x16x32_bf16(af[i], bf_[j], acc[i][j], 0, 0, 0);
    }
  }

  #pragma unroll
  for (int i = 0; i < 4; i++)
    #pragma unroll
    for (int j = 0; j < 4; j++)
      #pragma unroll
      for (int rr = 0; rr < 4; rr++){
        int row = bm + wm*64 + i*16 + l4*4 + rr;
        int col = bn + wn*64 + j*16 + l15;
        float v = acc[i][j][rr];
        if (EPI == 0){
          outB[(size_t)row*ldoB + col] = f2bf(v);
        } else if (EPI == 1){
          outF[(size_t)row*ldoF + col] = v;
          if (col < 64) out2[(size_t)row*64 + col] = (col < 48) ? f2bf(v) : (unsigned short)0;
        } else if (EPI == 2){
          outB[(size_t)row*ldoB + col] = f2bf(softplusf_(v + bias[col]));
        } else if (EPI == 3){
          v += bias[col];
          float g = 0.5f*v*(1.f + erff(v*0.70710678118f));
          outB[(size_t)row*ldoB + col] = f2bf(g);
        } else if (EPI == 4){
          v += bias[col];
          float g = 0.5f*v*(1.f + erff(v*0.70710678118f));
          outQ[(size_t)row*ldoB + col] = f2fp8(g * nrmS[row]);
        } else {
          outQ[(size_t)row*ldoB + col] = f2fp8(v * nrmS[row]);
        }
      }
}

// ---------------- causal conv + silu: sliding window, 8-wide load batch ----------------
__global__ __launch_bounds__(256) void k_conv_silu(const unsigned short* __restrict__ xz,
                                                   const float* __restrict__ conv_w,
                                                   const float* __restrict__ conv_b,
                                                   unsigned short* __restrict__ u){
  int c = blockIdx.x*256 + threadIdx.x;   // 0..1535
  int t0 = blockIdx.y*CT;
  float w0 = conv_w[c*4], w1 = conv_w[c*4+1], w2 = conv_w[c*4+2], w3 = conv_w[c*4+3];
  float bb = conv_b[c];
  const unsigned short* xp = xz + c;      // column base, row stride 3072
  float x0 = (t0 >= 3) ? bf2f(xp[(size_t)(t0-3)*3072]) : 0.f;
  float x1 = (t0 >= 2) ? bf2f(xp[(size_t)(t0-2)*3072]) : 0.f;
  float x2 = (t0 >= 1) ? bf2f(xp[(size_t)(t0-1)*3072]) : 0.f;
  unsigned short* up = u + (size_t)t0*DIM + c;
  for (int r0 = 0; r0 < CT; r0 += 8){
    unsigned short xb[8];
    #pragma unroll
    for (int j = 0; j < 8; j++) xb[j] = xp[(size_t)(t0+r0+j)*3072];
    #pragma unroll
    for (int j = 0; j < 8; j++){
      float x3 = bf2f(xb[j]);
      float acc = bb + x0*w0 + x1*w1 + x2*w2 + x3*w3;
      up[(r0+j)*DIM] = f2bf(acc * sigmoidf_(acc));
      x0 = x1; x1 = x2; x2 = x3;
    }
  }
}

// ---------------- selective scan: single sequential pass + parallel correction ----------------
__device__ __forceinline__ void pow_tree(float e1, float dA[16]){
  float e2 = e1*e1, e4 = e2*e2, e8 = e4*e4;
  dA[0]=e1;      dA[1]=e2;      dA[2]=e2*e1;   dA[3]=e4;
  dA[4]=e4*e1;   dA[5]=e4*e2;   dA[6]=e4*dA[2];dA[7]=e8;
  dA[8]=e8*e1;   dA[9]=e8*e2;   dA[10]=e8*dA[2];dA[11]=e8*e4;
  dA[12]=e8*dA[4];dA[13]=e8*dA[5];dA[14]=e8*dA[6];dA[15]=e8*e8;
}

// scanA': local recurrence + C-dot; stores pre-gate ylocal (bf16), hend, aprod
// fast path: 8-step register batch of dt/u loads (MLP depth 16 vs 2)
__global__ __launch_bounds__(256) void k_scanA(
    const unsigned short* __restrict__ delta, const unsigned short* __restrict__ u,
    const float* __restrict__ dbc, const float* __restrict__ A_log,
    const float* __restrict__ D_param,
    float* __restrict__ hend, float* __restrict__ aprod,
    unsigned short* __restrict__ ylocal)
{
  __shared__ float sBC[CL][32];
  int tid = threadIdx.x;
  int c = blockIdx.x*256 + tid;
  int k = blockIdx.y;
  float al2[16];
  #pragma unroll
  for (int s = 0; s < 16; s++) al2[s] = -expf(A_log[(size_t)c*16 + s]) * LOG2E;
  bool fast = true;
  #pragma unroll
  for (int s = 1; s < 16; s++)
    fast = fast && (fabsf(al2[s] - (float)(s+1)*al2[0]) <= 1e-4f*fabsf(al2[s]));
  float Dc = D_param[c];
  float h[16];
  #pragma unroll
  for (int s = 0; s < 16; s++) h[s] = 0.f;
  float sdt = 0.f;
  for (int idx = tid; idx < CL*32; idx += 256){
    int t = idx >> 5, j = idx & 31;
    sBC[t][j] = dbc[(size_t)(k*CL + t)*128 + 48 + j];
  }
  __syncthreads();
  const unsigned short* dp = delta + (size_t)k*CL*DIM + c;
  const unsigned short* up = u + (size_t)k*CL*DIM + c;
  unsigned short* yp = ylocal + (size_t)k*CL*DIM + c;
  if (fast){
    for (int t0 = 0; t0 < CL; t0 += 8){
      unsigned short dtb[8], uub[8];
      #pragma unroll
      for (int j = 0; j < 8; j++){
        dtb[j] = dp[(t0+j)*DIM];
        uub[j] = up[(t0+j)*DIM];
      }
      #pragma unroll
      for (int j = 0; j < 8; j++){
        int t = t0 + j;
        float dt = bf2f(dtb[j]), uu = bf2f(uub[j]);
        f32x4 Bv[4], Cv[4];
        #pragma unroll
        for (int q = 0; q < 4; q++){
          Bv[q] = *(const f32x4*)&sBC[t][q*4];
          Cv[q] = *(const f32x4*)&sBC[t][16 + q*4];
        }
        float dtu = dt*uu;
        sdt += dt;
        float dA[16];
        pow_tree(EXP2RAW(dt*al2[0]), dA);
        float ap[4] = {0.f,0.f,0.f,0.f};
        #pragma unroll
        for (int s = 0; s < 16; s++){
          h[s] = h[s]*dA[s] + dtu*Bv[s>>2][s&3];
          ap[s>>2] += h[s]*Cv[s>>2][s&3];
        }
        float accv = (ap[0]+ap[1]) + (ap[2]+ap[3]);
        yp[t*DIM] = f2bf(accv + uu*Dc);      // pre-gate local y
      }
    }
  } else {
    unsigned short dtn = dp[0], uun = up[0];
    #pragma unroll 2
    for (int t = 0; t < CL; t++){
      float dt = bf2f(dtn), uu = bf2f(uun);
      int tn = (t+1 < CL) ? t+1 : t;
      dtn = dp[tn*DIM]; uun = up[tn*DIM];
      f32x4 Bv[4], Cv[4];
      #pragma unroll
      for (int q = 0; q < 4; q++){
        Bv[q] = *(const f32x4*)&sBC[t][q*4];
        Cv[q] = *(const f32x4*)&sBC[t][16 + q*4];
      }
      float dtu = dt*uu;
      sdt += dt;
      float ap[4] = {0.f,0.f,0.f,0.f};
      #pragma unroll
      for (int s = 0; s < 16; s++){
        float dA = EXP2RAW(dt*al2[s]);
        h[s] = h[s]*dA + dtu*Bv[s>>2][s&3];
        ap[s>>2] += h[s]*Cv[s>>2][s&3];
      }
      float accv = (ap[0]+ap[1]) + (ap[2]+ap[3]);
      yp[t*DIM] = f2bf(accv + uu*Dc);
    }
  }
  size_t base = ((size_t)k*DIM + c)*16;
  #pragma unroll
  for (int s = 0; s < 16; s += 4){
    *(f32x4*)&hend[base+s]  = (f32x4){h[s],h[s+1],h[s+2],h[s+3]};
    *(f32x4*)&aprod[base+s] = (f32x4){EXP2RAW(al2[s]*sdt),EXP2RAW(al2[s+1]*sdt),
                                      EXP2RAW(al2[s+2]*sdt),EXP2RAW(al2[s+3]*sdt)};
  }
}

// scanB: 8-deep load prefetch (bit-identical ordering)
__global__ __launch_bounds__(256) void k_scanB(float* __restrict__ hend, const float* __restrict__ aprod){
  int i = blockIdx.x*256 + threadIdx.x;
  float H = 0.f;
  for (int k0 = 0; k0 < NCH; k0 += 8){
    float e[8], ap[8];
    #pragma unroll
    for (int j = 0; j < 8; j++){
      size_t o = (size_t)(k0+j)*DIM*16 + i;
      e[j] = hend[o]; ap[j] = aprod[o];
    }
    #pragma unroll
    for (int j = 0; j < 8; j++){
      size_t o = (size_t)(k0+j)*DIM*16 + i;
      hend[o] = H;
      H = e[j] + ap[j]*H;
    }
  }
}

// scanCorr: y[t] = (ylocal[t] + sum_s C[t][s]*Hin[s]*2^(al2[s]*cumdt[t])) * silu(z[t])
// Early-exit once 2^(alSlow*cum) < 2^-33; gate-only tail. 8-step register batching.
__global__ __launch_bounds__(256) void k_scanCorr(
    const unsigned short* __restrict__ delta, const unsigned short* __restrict__ xz,
    const float* __restrict__ dbc, const float* __restrict__ A_log,
    const float* __restrict__ hin, unsigned short* __restrict__ y)
{
  __shared__ float sC[CL][16];
  int tid = threadIdx.x;
  int c = blockIdx.x*256 + tid;
  int k = blockIdx.y;
  float al2[16];
  #pragma unroll
  for (int s = 0; s < 16; s++) al2[s] = -expf(A_log[(size_t)c*16 + s]) * LOG2E;
  bool fast = true;
  #pragma unroll
  for (int s = 1; s < 16; s++)
    fast = fast && (fabsf(al2[s] - (float)(s+1)*al2[0]) <= 1e-4f*fabsf(al2[s]));
  float alSlow = al2[0];
  #pragma unroll
  for (int s = 1; s < 16; s++) alSlow = fmaxf(alSlow, al2[s]);
  float Hin[16];
  size_t base = ((size_t)k*DIM + c)*16;
  #pragma unroll
  for (int s = 0; s < 16; s += 4){
    f32x4 v = *(const f32x4*)&hin[base+s];
    Hin[s] = v.x; Hin[s+1] = v.y; Hin[s+2] = v.z; Hin[s+3] = v.w;
  }
  for (int idx = tid; idx < CL*16; idx += 256){
    int t = idx >> 4, j = idx & 15;
    sC[t][j] = dbc[(size_t)(k*CL + t)*128 + 64 + j];
  }
  __syncthreads();
  const unsigned short* dp = delta + (size_t)k*CL*DIM + c;
  const unsigned short* zp = xz + (size_t)k*CL*3072 + 1536 + c;
  unsigned short* yp = y + (size_t)k*CL*DIM + c;
  float cum = 0.f;
  int t = 0;
  if (fast){
    bool done = false;
    for (int t0 = 0; t0 < CL && !done; t0 += 8){
      unsigned short dtb[8], zzb[8], ylb[8];
      #pragma unroll
      for (int j = 0; j < 8; j++){
        dtb[j] = dp[(t0+j)*DIM];
        zzb[j] = zp[(t0+j)*3072];
        ylb[j] = yp[(t0+j)*DIM];
      }
      #pragma unroll
      for (int j = 0; j < 8; j++){
        float dt = bf2f(dtb[j]);
        cum += dt;
        float e1 = EXP2RAW(cum*al2[0]);
        if (e1 < 0x1p-33f){ t = t0 + j; done = true; break; }
        float dA[16];
        pow_tree(e1, dA);
        f32x4 Cv[4];
        #pragma unroll
        for (int q = 0; q < 4; q++) Cv[q] = *(const f32x4*)&sC[t0+j][q*4];
        float ap[4] = {0.f,0.f,0.f,0.f};
        #pragma unroll
        for (int s = 0; s < 16; s++)
          ap[s>>2] += Hin[s]*dA[s]*Cv[s>>2][s&3];
        float corr = (ap[0]+ap[1]) + (ap[2]+ap[3]);
        float yl = bf2f(ylb[j]);
        float zz = bf2f(zzb[j]);
        yp[(t0+j)*DIM] = f2bf((yl + corr) * (zz * sigmoidf_(zz)));
      }
      if (!done) t = t0 + 8;
    }
  } else {
    for (; t < CL; t++){
      float dt = bf2f(dp[t*DIM]);
      cum += dt;
      if (EXP2RAW(cum*alSlow) < 0x1p-33f) break;
      f32x4 Cv[4];
      #pragma unroll
      for (int q = 0; q < 4; q++) Cv[q] = *(const f32x4*)&sC[t][q*4];
      float ap[4] = {0.f,0.f,0.f,0.f};
      #pragma unroll
      for (int s = 0; s < 16; s++)
        ap[s>>2] += Hin[s]*EXP2RAW(cum*al2[s])*Cv[s>>2][s&3];
      float corr = (ap[0]+ap[1]) + (ap[2]+ap[3]);
      float yl = bf2f(yp[t*DIM]);
      float zz = bf2f(zp[t*3072]);
      float yv = (yl + corr) * (zz * sigmoidf_(zz));
      yp[t*DIM] = f2bf(yv);
    }
  }
  // gate-only tail (batched)
  for (; t + 7 < CL; t += 8){
    unsigned short zzb[8], ylb[8];
    #pragma unroll
    for (int j = 0; j < 8; j++){
      ylb[j] = yp[(t+j)*DIM];
      zzb[j] = zp[(t+j)*3072];
    }
    #pragma unroll
    for (int j = 0; j < 8; j++){
      float yl = bf2f(ylb[j]);
      float zz = bf2f(zzb[j]);
      yp[(t+j)*DIM] = f2bf(yl * (zz * sigmoidf_(zz)));
    }
  }
  for (; t < CL; t++){
    float yl = bf2f(yp[t*DIM]);
    float zz = bf2f(zp[t*3072]);
    yp[t*DIM] = f2bf(yl * (zz * sigmoidf_(zz)));
  }
}

// ---------------- GCN aggregation (fp8 rows; HW cvt decode, 8-edge MLP unroll) ----------------
__global__ __launch_bounds__(192) void k_aggregate(
    const unsigned char* __restrict__ hq, const int* __restrict__ row_ptr,
    const int* __restrict__ csr_src, const float* __restrict__ normD,
    unsigned short* __restrict__ m)
{
  int d = blockIdx.x; int tid = threadIdx.x;
  int e0 = row_ptr[d], e1 = row_ptr[d+1];
  float a0 = 0.f, a1 = 0.f, a2 = 0.f, a3 = 0.f;
#if __has_builtin(__builtin_amdgcn_cvt_f32_fp8)
  int e = e0;
  for (; e + 7 < e1; e += 8){
    int sx[8];
    #pragma unroll
    for (int j = 0; j < 8; j++) sx[j] = csr_src[e+j];
    unsigned int w[8];
    #pragma unroll
    for (int j = 0; j < 8; j++) w[j] = *((const unsigned int*)(hq + (size_t)sx[j]*DF) + tid);
    a0 += (__builtin_amdgcn_cvt_f32_fp8(w[0], 0) + __builtin_amdgcn_cvt_f32_fp8(w[1], 0))
        + (__builtin_amdgcn_cvt_f32_fp8(w[2], 0) + __builtin_amdgcn_cvt_f32_fp8(w[3], 0));
    a1 += (__builtin_amdgcn_cvt_f32_fp8(w[0], 1) + __builtin_amdgcn_cvt_f32_fp8(w[1], 1))
        + (__builtin_amdgcn_cvt_f32_fp8(w[2], 1) + __builtin_amdgcn_cvt_f32_fp8(w[3], 1));
    a2 += (__builtin_amdgcn_cvt_f32_fp8(w[0], 2) + __builtin_amdgcn_cvt_f32_fp8(w[1], 2))
        + (__builtin_amdgcn_cvt_f32_fp8(w[2], 2) + __builtin_amdgcn_cvt_f32_fp8(w[3], 2));
    a3 += (__builtin_amdgcn_cvt_f32_fp8(w[0], 3) + __builtin_amdgcn_cvt_f32_fp8(w[1], 3))
        + (__builtin_amdgcn_cvt_f32_fp8(w[2], 3) + __builtin_amdgcn_cvt_f32_fp8(w[3], 3));
    a0 += (__builtin_amdgcn_cvt_f32_fp8(w[4], 0) + __builtin_amdgcn_cvt_f32_fp8(w[5], 0))
        + (__builtin_amdgcn_cvt_f32_fp8(w[6], 0) + __builtin_amdgcn_cvt_f32_fp8(w[7], 0));
    a1 += (__builtin_amdgcn_cvt_f32_fp8(w[4], 1) + __builtin_amdgcn_cvt_f32_fp8(w[5], 1))
        + (__builtin_amdgcn_cvt_f32_fp8(w[6], 1) + __builtin_amdgcn_cvt_f32_fp8(w[7], 1));
    a2 += (__builtin_amdgcn_cvt_f32_fp8(w[4], 2) + __builtin_amdgcn_cvt_f32_fp8(w[5], 2))
        + (__builtin_amdgcn_cvt_f32_fp8(w[6], 2) + __builtin_amdgcn_cvt_f32_fp8(w[7], 2));
    a3 += (__builtin_amdgcn_cvt_f32_fp8(w[4], 3) + __builtin_amdgcn_cvt_f32_fp8(w[5], 3))
        + (__builtin_amdgcn_cvt_f32_fp8(w[6], 3) + __builtin_amdgcn_cvt_f32_fp8(w[7], 3));
  }
  for (; e + 3 < e1; e += 4){
    int s0 = csr_src[e],   s1 = csr_src[e+1];
    int s2 = csr_src[e+2], s3 = csr_src[e+3];
    unsigned int w0 = *((const unsigned int*)(hq + (size_t)s0*DF) + tid);
    unsigned int w1 = *((const unsigned int*)(hq + (size_t)s1*DF) + tid);
    unsigned int w2 = *((const unsigned int*)(hq + (size_t)s2*DF) + tid);
    unsigned int w3 = *((const unsigned int*)(hq + (size_t)s3*DF) + tid);
    a0 += (__builtin_amdgcn_cvt_f32_fp8(w0, 0) + __builtin_amdgcn_cvt_f32_fp8(w1, 0))
        + (__builtin_amdgcn_cvt_f32_fp8(w2, 0) + __builtin_amdgcn_cvt_f32_fp8(w3, 0));
    a1 += (__builtin_amdgcn_cvt_f32_fp8(w0, 1) + __builtin_amdgcn_cvt_f32_fp8(w1, 1))
        + (__builtin_amdgcn_cvt_f32_fp8(w2, 1) + __builtin_amdgcn_cvt_f32_fp8(w3, 1));
    a2 += (__builtin_amdgcn_cvt_f32_fp8(w0, 2) + __builtin_amdgcn_cvt_f32_fp8(w1, 2))
        + (__builtin_amdgcn_cvt_f32_fp8(w2, 2) + __builtin_amdgcn_cvt_f32_fp8(w3, 2));
    a3 += (__builtin_amdgcn_cvt_f32_fp8(w0, 3) + __builtin_amdgcn_cvt_f32_fp8(w1, 3))
        + (__builtin_amdgcn_cvt_f32_fp8(w2, 3) + __builtin_amdgcn_cvt_f32_fp8(w3, 3));
  }
  for (; e < e1; e++){
    int s0 = csr_src[e];
    unsigned int w0 = *((const unsigned int*)(hq + (size_t)s0*DF) + tid);
    a0 += __builtin_amdgcn_cvt_f32_fp8(w0, 0);
    a1 += __builtin_amdgcn_cvt_f32_fp8(w0, 1);
    a2 += __builtin_amdgcn_cvt_f32_fp8(w0, 2);
    a3 += __builtin_amdgcn_cvt_f32_fp8(w0, 3);
  }
  float nd = normD[d] * (1.f/H8SCALE);   // HW decode yields true e4m3 value
#else
  for (int e = e0; e < e1; e++){
    int sI = csr_src[e];
    unsigned int w = *((const unsigned int*)(hq + (size_t)sI*DF) + tid);
    a0 += fp8bits(w & 255u);
    a1 += fp8bits((w >> 8) & 255u);
    a2 += fp8bits((w >> 16) & 255u);
    a3 += fp8bits(w >> 24);
  }
  float nd = normD[d] * 0x1p+114f;       // 2^120 decode scale / H8SCALE(=2^6)
#endif
  uint2 o;
  o.x = (unsigned int)f2bf(a0*nd) | ((unsigned int)f2bf(a1*nd) << 16);
  o.y = (unsigned int)f2bf(a2*nd) | ((unsigned int)f2bf(a3*nd) << 16);
  *((uint2*)(m + (size_t)d*DF) + tid) = o;
}

// ---------------- finals (causal + gfeat merged; gfeat 768 blocks x 32 rows) ----------------
__global__ __launch_bounds__(256) void k_final(const unsigned short* __restrict__ h,
                                               const float* __restrict__ W_c,
                                               const float* __restrict__ b_c,
                                               float* __restrict__ out){
  int b = blockIdx.x;
  if (b < 2048){
    int wv = threadIdx.x >> 6, lane = threadIdx.x & 63;
    int r = b*4 + wv;
    float s = 0.f;
    #pragma unroll
    for (int j = 0; j < 12; j++){
      int cidx = lane + 64*j;
      s += bf2f(h[(size_t)r*DF + cidx]) * W_c[cidx];
    }
    s += __shfl_xor(s, 32); s += __shfl_xor(s, 16); s += __shfl_xor(s, 8);
    s += __shfl_xor(s, 4);  s += __shfl_xor(s, 2);  s += __shfl_xor(s, 1);
    if (lane == 0){
      float a = s + b_c[0];
      float cz = 1.f/(1.f + expf(-a));   // precise libm for f32 output
      out[DF + r] = cz;
      out[DF + NN + r] = (cz > 0.7f) ? 1.f : 0.f;
    }
  } else {
    int g = b - 2048;                 // 0..767
    int col = (g % 3)*256 + threadIdx.x;
    int r0 = (g / 3)*32;              // 256 chunks x 32 rows
    float s = 0.f;
    #pragma unroll 4
    for (int r = r0; r < r0 + 32; r++) s += bf2f(h[(size_t)r*DF + col]);
    atomicAdd(&out[col], s * (1.f/8192.f));
  }
}

// ---------------- launch ----------------
extern "C" void kernel_launch(void* const* d_in, const int* in_sizes, int n_in,
                              void* d_out, int out_size, void* d_ws, size_t ws_size,
                              hipStream_t stream) {
  const float* node_feats = (const float*)d_in[0];
  const int*   timestamps = (const int*)d_in[1];
  const int*   ei         = (const int*)d_in[2];
  const int*   e_src = ei;
  const int*   e_dst = ei + NE_;
  const float* W_in    = (const float*)d_in[3];
  const float* conv_w  = (const float*)d_in[4];
  const float* conv_b  = (const float*)d_in[5];
  const float* W_xproj = (const float*)d_in[6];
  const float* W_dt    = (const float*)d_in[7];
  const float* b_dt    = (const float*)d_in[8];
  const float* A_log   = (const float*)d_in[9];
  const float* D_param = (const float*)d_in[10];
  const float* W_out   = (const float*)d_in[11];
  const float* Wg      = (const float*)d_in[12];
  const float* bg      = (const float*)d_in[13];
  const float* W_c     = (const float*)d_in[14];
  const float* b_c     = (const float*)d_in[15];
  float* out = (float*)d_out;

  char* ws = (char*)d_ws;
  size_t off = 0;
  auto alloc = [&](size_t bytes) -> char* {
    char* p = ws + off; off += (bytes + 255) & ~(size_t)255; return p;
  };
  unsigned short* WinT   = (unsigned short*)alloc((size_t)3072*768*2);
  unsigned short* WxT    = (unsigned short*)alloc((size_t)128*1536*2);
  unsigned short* WdtT   = (unsigned short*)alloc((size_t)1536*64*2);
  unsigned short* WoutT  = (unsigned short*)alloc((size_t)768*1536*2);
  unsigned short* WgT    = (unsigned short*)alloc((size_t)3*768*768*2);
  unsigned short* seq    = (unsigned short*)alloc((size_t)NN*DF*2);
  unsigned short* xz     = (unsigned short*)alloc((size_t)NN*3072*2);
  unsigned short* ubuf   = (unsigned short*)alloc((size_t)NN*DIM*2);
  float*          dbc    = (float*)alloc((size_t)NN*128*4);
  unsigned short* dt48   = (unsigned short*)alloc((size_t)NN*64*2);
  unsigned short* deltaB = (unsigned short*)alloc((size_t)NN*DIM*2);
  unsigned short* ybuf   = (unsigned short*)alloc((size_t)NN*DIM*2);
  unsigned short* hbuf   = (unsigned short*)alloc((size_t)NN*DF*2);
  unsigned short* mbuf   = (unsigned short*)alloc((size_t)NN*DF*2);
  unsigned char*  hq     = (unsigned char*)alloc((size_t)NN*DF);
  int*   pos    = (int*)alloc((size_t)NN*4);
  int*   degS   = (int*)alloc((size_t)2*NN*4);
  int*   degD   = degS + NN;
  float* normS  = (float*)alloc((size_t)NN*4);
  float* normD  = (float*)alloc((size_t)NN*4);
  int*   rowp   = (int*)alloc((size_t)(NN+1)*4);
  int*   cursor = (int*)alloc((size_t)NN*4);
  int*   csr    = (int*)alloc((size_t)NE_*4);

  // scan summaries: hend aliases seq (dead after G1); aprod aliases mbuf
  // (first written by k_aggregate, after scanB consumed aprod)
  float* hend  = (float*)seq;
  float* aprod = (float*)mbuf;

  // 1. weight prep (LDS-tiled transpose) + zero-init (pos/degS+degD/out[0:768])
  k_prep<<<1465, 256, 0, stream>>>(W_in, W_xproj, W_dt, W_out, Wg,
                                   WinT, WxT, WdtT, WoutT, WgT,
                                   pos, degS, out);
  // 2. rank + degree count
  k_rank_deg<<<2048, 256, 0, stream>>>(timestamps, pos, e_src, e_dst, degS, degD);
  // 3. norms + rowptr
  k_graphfix<<<9, 1024, 0, stream>>>(degS, degD, normS, normD, rowp, cursor);
  // 4. gather + csr fill
  k_scatter<<<NN + 1024, 256, 0, stream>>>(node_feats, pos, seq, e_src, e_dst, cursor, csr);

  // G1: xz = seq @ W_in
  k_gemm<0><<<64*24, 256, 0, stream>>>(seq, WinT, 3072, 768, 768, 768,
                                       nullptr, 0, xz, 3072, nullptr, nullptr, nullptr, nullptr);
  // conv + silu -> u (sliding-window)
  k_conv_silu<<<dim3(6, NN/CT), 256, 0, stream>>>(xz, conv_w, conv_b, ubuf);
  // G2: dbc = u @ W_xproj; also dt48
  k_gemm<1><<<64*1, 256, 0, stream>>>(ubuf, WxT, 128, 1536, 1536, 1536,
                                      dbc, 128, nullptr, 0, nullptr, dt48, nullptr, nullptr);
  // G3: delta = softplus(...) -> bf16
  k_gemm<2><<<64*12, 256, 0, stream>>>(dt48, WdtT, 1536, 64, 64, 64,
                                       nullptr, 0, deltaB, 1536, b_dt, nullptr, nullptr, nullptr);
  // scan: single sequential pass + combine + parallel correction
  k_scanA<<<dim3(DIM/256, NCH), 256, 0, stream>>>(deltaB, ubuf, dbc, A_log, D_param, hend, aprod, ybuf);
  k_scanB<<<96, 256, 0, stream>>>(hend, aprod);
  k_scanCorr<<<dim3(DIM/256, NCH), 256, 0, stream>>>(deltaB, xz, dbc, A_log, hend, ybuf);
  // G4: h = y @ W_out -> fp8 (normS-prescaled)
  k_gemm<5><<<64*6, 256, 0, stream>>>(ybuf, WoutT, 768, 1536, 1536, 1536,
                                      nullptr, 0, nullptr, 768, nullptr, nullptr, hq, normS);
  // 3 GCN layers
  k_aggregate<<<NN, 192, 0, stream>>>(hq, rowp, csr, normD, mbuf);
  k_gemm<4><<<64*6, 256, 0, stream>>>(mbuf, WgT, 768, 768, 768, 768,
                                      nullptr, 0, nullptr, 768, bg, nullptr, hq, normS);
  k_aggregate<<<NN, 192, 0, stream>>>(hq, rowp, csr, normD, mbuf);
  k_gemm<4><<<64*6, 256, 0, stream>>>(mbuf, WgT + (size_t)768*768, 768, 768, 768, 768,
                                      nullptr, 0, nullptr, 768, bg + 768, nullptr, hq, normS);
  k_aggregate<<<NN, 192, 0, stream>>>(hq, rowp, csr, normD, mbuf);
  k_gemm<3><<<64*6, 256, 0, stream>>>(mbuf, WgT + (size_t)2*768*768, 768, 768, 768, 768,
                                      nullptr, 0, hbuf, 768, bg + 2*768, nullptr, nullptr, nullptr);
  // finals (causal + graph_feat)
  k_final<<<2816, 256, 0, stream>>>(hbuf, W_c, b_c, out);
}

// Round 36
// 452.928 us; speedup vs baseline: 1.0438x; 1.0064x over previous
//
#include <hip/hip_runtime.h>
#include <math.h>

#define NN 8192
#define DF 768
#define NE_ 262144
#define DIM 1536
#define DSN 16
#define NCH 128
#define CL  64   // NN / NCH
#define CT  64   // conv time-block

typedef short short8 __attribute__((ext_vector_type(8)));
typedef float f32x4 __attribute__((ext_vector_type(4)));
typedef unsigned short us4 __attribute__((ext_vector_type(4)));

__device__ __forceinline__ float bf2f(unsigned short u){
  unsigned int v = ((unsigned int)u) << 16; float f; __builtin_memcpy(&f, &v, 4); return f;
}
__device__ __forceinline__ unsigned short f2bf(float f){
  unsigned int x; __builtin_memcpy(&x, &f, 4);
  x += 0x7fffu + ((x >> 16) & 1u);
  return (unsigned short)(x >> 16);
}
#define EXP2RAW(x) __builtin_amdgcn_exp2f(x)   // single v_exp_f32
#define LOG2E 1.44269504088896f
#define LN2   0.69314718055995f
#define H8SCALE 64.f
// fast sigmoid: native exp2 + rcp
__device__ __forceinline__ float sigmoidf_(float x){
  return 1.f/(1.f + EXP2RAW(-x*LOG2E));
}
// fast softplus: ln2 * log2(1 + 2^(v*log2e)); exact passthrough for large v
__device__ __forceinline__ float softplusf_(float v){
  if (v > 20.f) return v;
  return LN2 * __log2f(1.f + EXP2RAW(v*LOG2E));
}

// ---- fp8 e4m3fn encode ----
__device__ __forceinline__ unsigned char f2fp8(float v){
  float y = v * H8SCALE;
#if __has_builtin(__builtin_amdgcn_cvt_pk_fp8_f32)
  return (unsigned char)(__builtin_amdgcn_cvt_pk_fp8_f32(y, y, 0, false) & 0xff);
#else
  unsigned int u; __builtin_memcpy(&u, &y, 4);
  unsigned char s = (unsigned char)((u >> 24) & 0x80);
  float a = fabsf(y);
  if (a >= 448.f) return (unsigned char)(s | 0x7E);
  if (a < 0x1p-10f) return s;
  unsigned int ab = u & 0x7fffffffu;
  int ef = (int)(ab >> 23) - 127;
  int qe = ef - 3; if (qe < -9) qe = -9;
  float q; { unsigned int qb = (unsigned int)(qe + 127) << 23; __builtin_memcpy(&q, &qb, 4); }
  float n = rintf(a / q);
  float m = n * q;
  unsigned int mb; __builtin_memcpy(&mb, &m, 4);
  int E = (int)(mb >> 23) - 127 + 7;
  unsigned char out;
  if (E <= 0) out = (unsigned char)rintf(m * 512.f);
  else        out = (unsigned char)((E << 3) | ((mb >> 20) & 7));
  return (unsigned char)(s | out);
#endif
}
// software decode bit-trick: result = e4m3(b) * 2^-120 (exact); caller folds 2^120.
__device__ __forceinline__ float fp8bits(unsigned int b){
  unsigned int t = ((b & 0x80u) << 24) | ((b & 0x7fu) << 20);
  float f; __builtin_memcpy(&f, &t, 4); return f;
}

// async global->LDS, 16B per lane
__device__ __forceinline__ void gl_lds16(const unsigned short* g, unsigned short* l){
  __builtin_amdgcn_global_load_lds(
      (const __attribute__((address_space(1))) unsigned int*)g,
      (__attribute__((address_space(3))) unsigned int*)l,
      16, 0, 0);
}

// ---------------- weight prep: LDS-tiled transpose (coalesced both sides) ----------------
// 64x64 tiles; pitch 65 kills bank conflicts. Output element = f2bf(in[k*N+n]) --
// bit-identical to the old per-element path, including zero padding.
__global__ __launch_bounds__(256) void k_prep(
    const float* __restrict__ W_in, const float* __restrict__ W_xproj,
    const float* __restrict__ W_dt, const float* __restrict__ W_out,
    const float* __restrict__ Wg,
    unsigned short* __restrict__ WinT, unsigned short* __restrict__ WxT,
    unsigned short* __restrict__ WdtT, unsigned short* __restrict__ WoutT,
    unsigned short* __restrict__ WgT,
    int* __restrict__ pos, int* __restrict__ degS, float* __restrict__ outv)
{
  int b = blockIdx.x;
  int tid = threadIdx.x;
  if (b >= 1368){
    if (b < 1400)       pos[(b-1368)*256 + tid] = 0;
    else if (b < 1464)  degS[(b-1400)*256 + tid] = 0;   // degS+degD contiguous 2*NN
    else { outv[tid] = 0.f; outv[256+tid] = 0.f; outv[512+tid] = 0.f; }
    return;
  }
  // decode matrix + tile
  const float* in; unsigned short* out; int K, N, Kp, Np, kt, nt;
  if (b < 576){        in = W_in;    out = WinT;  K = 768;  N = 3072; Kp = 768;  Np = 3072;
                       kt = b / 48;  nt = b % 48; }
  else if (b < 624){   int l = b - 576;
                       in = W_xproj; out = WxT;   K = 1536; N = 80;   Kp = 1536; Np = 128;
                       kt = l >> 1;  nt = l & 1; }
  else if (b < 648){   int l = b - 624;
                       in = W_dt;    out = WdtT;  K = 48;   N = 1536; Kp = 64;   Np = 1536;
                       kt = 0;       nt = l; }
  else if (b < 936){   int l = b - 648;
                       in = W_out;   out = WoutT; K = 1536; N = 768;  Kp = 1536; Np = 768;
                       kt = l / 12;  nt = l % 12; }
  else {               int l = b - 936;
                       int g = l / 144; int r = l % 144;
                       in = Wg + (size_t)g*768*768; out = WgT + (size_t)g*768*768;
                       K = 768; N = 768; Kp = 768; Np = 768;
                       kt = r / 12;  nt = r % 12; }
  int k0 = kt*64, n0 = nt*64;
  __shared__ float tl[64][65];
  int ln = tid & 63;   // inner (contiguous) index
  int lk = tid >> 6;   // 0..3
  #pragma unroll
  for (int kk = lk; kk < 64; kk += 4){
    int gk = k0 + kk, gn = n0 + ln;
    float v = (gk < K && gn < N) ? in[(size_t)gk*N + gn] : 0.f;
    tl[kk][ln] = v;
  }
  __syncthreads();
  #pragma unroll
  for (int nn = lk; nn < 64; nn += 4){
    int gn2 = n0 + nn, gk2 = k0 + ln;
    if (gn2 < Np && gk2 < Kp)
      out[(size_t)gn2*Kp + gk2] = f2bf(tl[ln][nn]);
  }
}

// ---------------- rank + deg_count (merged) ----------------
__global__ __launch_bounds__(256) void k_rank_deg(const int* __restrict__ ts, int* __restrict__ pos,
                                                  const int* __restrict__ esrc, const int* __restrict__ edst,
                                                  int* __restrict__ degS, int* __restrict__ degD){
  int b = blockIdx.x;
  if (b < 1024){
    __shared__ int sT[256];
    int ic = b & 31, jc = b >> 5;
    int i = ic*256 + threadIdx.x;
    int my = ts[i];
    int c0 = jc*256;
    sT[threadIdx.x] = ts[c0 + threadIdx.x];
    __syncthreads();
    int r = 0;
    #pragma unroll 8
    for (int j = 0; j < 256; j++){
      int t = sT[j]; int jj = c0 + j;
      r += (t < my || (t == my && jj < i)) ? 1 : 0;
    }
    atomicAdd(&pos[i], r);
  } else {
    int e = (b-1024)*256 + threadIdx.x;
    atomicAdd(&degS[esrc[e]], 1); atomicAdd(&degD[edst[e]], 1);
  }
}

// ---------------- norms + rowptr (merged; 1024 threads) ----------------
__global__ __launch_bounds__(1024) void k_graphfix(const int* __restrict__ degS, const int* __restrict__ degD,
                                                   float* __restrict__ normS, float* __restrict__ normD,
                                                   int* __restrict__ row_ptr, int* __restrict__ cursor){
  int b = blockIdx.x;
  int tid = threadIdx.x;
  if (b < 8){
    int i = b*1024 + tid;
    normS[i] = rsqrtf(fmaxf((float)degS[i], 1.f));
    normD[i] = rsqrtf(fmaxf((float)degD[i], 1.f));
    return;
  }
  __shared__ int sp[1024];
  int base = tid*8;
  int loc[8]; int s = 0;
  #pragma unroll
  for (int j = 0; j < 8; j++){ loc[j] = degD[base+j]; s += loc[j]; }
  sp[tid] = s; __syncthreads();
  for (int o = 1; o < 1024; o <<= 1){
    int v = (tid >= o) ? sp[tid-o] : 0; __syncthreads();
    sp[tid] += v; __syncthreads();
  }
  int run = sp[tid] - s;
  #pragma unroll
  for (int j = 0; j < 8; j++){ row_ptr[base+j] = run; cursor[base+j] = run; run += loc[j]; }
  if (tid == 1023) row_ptr[NN] = sp[1023];
}

// ---------------- gather + csr_fill (merged; vectorized row copy) ----------------
__global__ __launch_bounds__(256) void k_scatter(const float* __restrict__ nf, const int* __restrict__ pos,
                                                 unsigned short* __restrict__ seq,
                                                 const int* __restrict__ esrc, const int* __restrict__ edst,
                                                 int* __restrict__ cursor, int* __restrict__ csr_src){
  int b = blockIdx.x;
  if (b < NN){
    int p = pos[b];
    const float* src = nf + (size_t)b*DF;
    unsigned short* dst = seq + (size_t)p*DF;
    for (int j = threadIdx.x; j < DF/4; j += 256){
      f32x4 v = *(const f32x4*)&src[j*4];
      us4 o = { f2bf(v.x), f2bf(v.y), f2bf(v.z), f2bf(v.w) };
      *(us4*)&dst[j*4] = o;
    }
  } else {
    int e = (b-NN)*256 + threadIdx.x;
    int d = edst[e];
    int p = atomicAdd(&cursor[d], 1);
    csr_src[p] = esrc[e];
  }
}

// ---------------- bf16 MFMA GEMM (128x128 tile, BK=64, 4 waves) ----------------
// XCD-chunked blockIdx swizzle (T1). EPI: 0 bf16; 1 f32+dt48; 2 softplus bf16;
// 3 gelu bf16; 4 gelu*normS fp8; 5 v*normS fp8
template<int EPI>
__global__ __launch_bounds__(256) void k_gemm(
    const unsigned short* __restrict__ A, const unsigned short* __restrict__ B,
    int N, int K, int lda, int ldb,
    float* __restrict__ outF, int ldoF,
    unsigned short* __restrict__ outB, int ldoB,
    const float* __restrict__ bias,
    unsigned short* __restrict__ out2,
    unsigned char* __restrict__ outQ,
    const float* __restrict__ nrmS)
{
  __shared__ unsigned short sA[2][128*32];
  __shared__ unsigned short sB[2][128*32];
  int tid = threadIdx.x;
  int tnc = N >> 7;
  int nwg = gridDim.x;
  int bid = blockIdx.x;
  int swz = (nwg & 7) ? bid : ((bid & 7)*(nwg >> 3) + (bid >> 3));
  int bm = (swz / tnc) << 7;
  int bn = (swz % tnc) << 7;
  int wv = tid >> 6, lane = tid & 63;
  int wm = wv >> 1, wn = wv & 1;
  int l15 = lane & 15, l4 = lane >> 4;

  f32x4 acc[4][4];
  #pragma unroll
  for (int i = 0; i < 4; i++)
    #pragma unroll
    for (int j = 0; j < 4; j++)
      acc[i][j] = (f32x4){0.f,0.f,0.f,0.f};

  int r0 = (wv*2)*16 + (lane >> 2);
  int r1 = r0 + 16;
  int cc = (lane & 3)*8;
  const unsigned short* gA0 = A + (size_t)(bm + r0)*lda + cc;
  const unsigned short* gA1 = A + (size_t)(bm + r1)*lda + cc;
  const unsigned short* gB0 = B + (size_t)(bn + r0)*ldb + cc;
  const unsigned short* gB1 = B + (size_t)(bn + r1)*ldb + cc;
  unsigned short* lA0 = &sA[0][(size_t)(wv*2)*512];
  unsigned short* lA1 = &sA[1][(size_t)(wv*2)*512];
  unsigned short* lB0 = &sB[0][(size_t)(wv*2)*512];
  unsigned short* lB1 = &sB[1][(size_t)(wv*2)*512];

  for (int k0 = 0; k0 < K; k0 += 64){
    __syncthreads();
    gl_lds16(gA0 + k0,      lA0);
    gl_lds16(gA1 + k0,      lA0 + 512);
    gl_lds16(gA0 + k0 + 32, lA1);
    gl_lds16(gA1 + k0 + 32, lA1 + 512);
    gl_lds16(gB0 + k0,      lB0);
    gl_lds16(gB1 + k0,      lB0 + 512);
    gl_lds16(gB0 + k0 + 32, lB1);
    gl_lds16(gB1 + k0 + 32, lB1 + 512);
    __syncthreads();
    #pragma unroll
    for (int h = 0; h < 2; h++){
      short8 af[4], bf_[4];
      #pragma unroll
      for (int i = 0; i < 4; i++){
        af[i]  = *(const short8*)&sA[h][(wm*64 + i*16 + l15)*32 + l4*8];
        bf_[i] = *(const short8*)&sB[h][(wn*64 + i*16 + l15)*32 + l4*8];
      }
      #pragma unroll
      for (int i = 0; i < 4; i++)
        #pragma unroll
        for (int j = 0; j < 4; j++)
          acc[i][j] = __builtin_amdgcn_mfma_f32_16x16x32_bf16(af[i], bf_[j], acc[i][j], 0, 0, 0);
    }
  }

  #pragma unroll
  for (int i = 0; i < 4; i++)
    #pragma unroll
    for (int j = 0; j < 4; j++)
      #pragma unroll
      for (int rr = 0; rr < 4; rr++){
        int row = bm + wm*64 + i*16 + l4*4 + rr;
        int col = bn + wn*64 + j*16 + l15;
        float v = acc[i][j][rr];
        if (EPI == 0){
          outB[(size_t)row*ldoB + col] = f2bf(v);
        } else if (EPI == 1){
          outF[(size_t)row*ldoF + col] = v;
          if (col < 64) out2[(size_t)row*64 + col] = (col < 48) ? f2bf(v) : (unsigned short)0;
        } else if (EPI == 2){
          outB[(size_t)row*ldoB + col] = f2bf(softplusf_(v + bias[col]));
        } else if (EPI == 3){
          v += bias[col];
          float g = 0.5f*v*(1.f + erff(v*0.70710678118f));
          outB[(size_t)row*ldoB + col] = f2bf(g);
        } else if (EPI == 4){
          v += bias[col];
          float g = 0.5f*v*(1.f + erff(v*0.70710678118f));
          outQ[(size_t)row*ldoB + col] = f2fp8(g * nrmS[row]);
        } else {
          outQ[(size_t)row*ldoB + col] = f2fp8(v * nrmS[row]);
        }
      }
}

// ---------------- causal conv + silu: sliding window, 8-wide load batch ----------------
__global__ __launch_bounds__(256) void k_conv_silu(const unsigned short* __restrict__ xz,
                                                   const float* __restrict__ conv_w,
                                                   const float* __restrict__ conv_b,
                                                   unsigned short* __restrict__ u){
  int c = blockIdx.x*256 + threadIdx.x;   // 0..1535
  int t0 = blockIdx.y*CT;
  float w0 = conv_w[c*4], w1 = conv_w[c*4+1], w2 = conv_w[c*4+2], w3 = conv_w[c*4+3];
  float bb = conv_b[c];
  const unsigned short* xp = xz + c;      // column base, row stride 3072
  float x0 = (t0 >= 3) ? bf2f(xp[(size_t)(t0-3)*3072]) : 0.f;
  float x1 = (t0 >= 2) ? bf2f(xp[(size_t)(t0-2)*3072]) : 0.f;
  float x2 = (t0 >= 1) ? bf2f(xp[(size_t)(t0-1)*3072]) : 0.f;
  unsigned short* up = u + (size_t)t0*DIM + c;
  for (int r0 = 0; r0 < CT; r0 += 8){
    unsigned short xb[8];
    #pragma unroll
    for (int j = 0; j < 8; j++) xb[j] = xp[(size_t)(t0+r0+j)*3072];
    #pragma unroll
    for (int j = 0; j < 8; j++){
      float x3 = bf2f(xb[j]);
      float acc = bb + x0*w0 + x1*w1 + x2*w2 + x3*w3;
      up[(r0+j)*DIM] = f2bf(acc * sigmoidf_(acc));
      x0 = x1; x1 = x2; x2 = x3;
    }
  }
}

// ---------------- selective scan: single sequential pass + parallel correction ----------------
__device__ __forceinline__ void pow_tree(float e1, float dA[16]){
  float e2 = e1*e1, e4 = e2*e2, e8 = e4*e4;
  dA[0]=e1;      dA[1]=e2;      dA[2]=e2*e1;   dA[3]=e4;
  dA[4]=e4*e1;   dA[5]=e4*e2;   dA[6]=e4*dA[2];dA[7]=e8;
  dA[8]=e8*e1;   dA[9]=e8*e2;   dA[10]=e8*dA[2];dA[11]=e8*e4;
  dA[12]=e8*dA[4];dA[13]=e8*dA[5];dA[14]=e8*dA[6];dA[15]=e8*e8;
}

// scanA': local recurrence + C-dot; stores pre-gate ylocal (bf16), hend, aprod
// fast path: 8-step register batch of dt/u loads (MLP depth 16 vs 2)
__global__ __launch_bounds__(256) void k_scanA(
    const unsigned short* __restrict__ delta, const unsigned short* __restrict__ u,
    const float* __restrict__ dbc, const float* __restrict__ A_log,
    const float* __restrict__ D_param,
    float* __restrict__ hend, float* __restrict__ aprod,
    unsigned short* __restrict__ ylocal)
{
  __shared__ float sBC[CL][32];
  int tid = threadIdx.x;
  int c = blockIdx.x*256 + tid;
  int k = blockIdx.y;
  float al2[16];
  #pragma unroll
  for (int s = 0; s < 16; s++) al2[s] = -expf(A_log[(size_t)c*16 + s]) * LOG2E;
  bool fast = true;
  #pragma unroll
  for (int s = 1; s < 16; s++)
    fast = fast && (fabsf(al2[s] - (float)(s+1)*al2[0]) <= 1e-4f*fabsf(al2[s]));
  float Dc = D_param[c];
  float h[16];
  #pragma unroll
  for (int s = 0; s < 16; s++) h[s] = 0.f;
  float sdt = 0.f;
  for (int idx = tid; idx < CL*32; idx += 256){
    int t = idx >> 5, j = idx & 31;
    sBC[t][j] = dbc[(size_t)(k*CL + t)*128 + 48 + j];
  }
  __syncthreads();
  const unsigned short* dp = delta + (size_t)k*CL*DIM + c;
  const unsigned short* up = u + (size_t)k*CL*DIM + c;
  unsigned short* yp = ylocal + (size_t)k*CL*DIM + c;
  if (fast){
    for (int t0 = 0; t0 < CL; t0 += 8){
      unsigned short dtb[8], uub[8];
      #pragma unroll
      for (int j = 0; j < 8; j++){
        dtb[j] = dp[(t0+j)*DIM];
        uub[j] = up[(t0+j)*DIM];
      }
      #pragma unroll
      for (int j = 0; j < 8; j++){
        int t = t0 + j;
        float dt = bf2f(dtb[j]), uu = bf2f(uub[j]);
        f32x4 Bv[4], Cv[4];
        #pragma unroll
        for (int q = 0; q < 4; q++){
          Bv[q] = *(const f32x4*)&sBC[t][q*4];
          Cv[q] = *(const f32x4*)&sBC[t][16 + q*4];
        }
        float dtu = dt*uu;
        sdt += dt;
        float dA[16];
        pow_tree(EXP2RAW(dt*al2[0]), dA);
        float ap[4] = {0.f,0.f,0.f,0.f};
        #pragma unroll
        for (int s = 0; s < 16; s++){
          h[s] = h[s]*dA[s] + dtu*Bv[s>>2][s&3];
          ap[s>>2] += h[s]*Cv[s>>2][s&3];
        }
        float accv = (ap[0]+ap[1]) + (ap[2]+ap[3]);
        yp[t*DIM] = f2bf(accv + uu*Dc);      // pre-gate local y
      }
    }
  } else {
    unsigned short dtn = dp[0], uun = up[0];
    #pragma unroll 2
    for (int t = 0; t < CL; t++){
      float dt = bf2f(dtn), uu = bf2f(uun);
      int tn = (t+1 < CL) ? t+1 : t;
      dtn = dp[tn*DIM]; uun = up[tn*DIM];
      f32x4 Bv[4], Cv[4];
      #pragma unroll
      for (int q = 0; q < 4; q++){
        Bv[q] = *(const f32x4*)&sBC[t][q*4];
        Cv[q] = *(const f32x4*)&sBC[t][16 + q*4];
      }
      float dtu = dt*uu;
      sdt += dt;
      float ap[4] = {0.f,0.f,0.f,0.f};
      #pragma unroll
      for (int s = 0; s < 16; s++){
        float dA = EXP2RAW(dt*al2[s]);
        h[s] = h[s]*dA + dtu*Bv[s>>2][s&3];
        ap[s>>2] += h[s]*Cv[s>>2][s&3];
      }
      float accv = (ap[0]+ap[1]) + (ap[2]+ap[3]);
      yp[t*DIM] = f2bf(accv + uu*Dc);
    }
  }
  size_t base = ((size_t)k*DIM + c)*16;
  #pragma unroll
  for (int s = 0; s < 16; s += 4){
    *(f32x4*)&hend[base+s]  = (f32x4){h[s],h[s+1],h[s+2],h[s+3]};
    *(f32x4*)&aprod[base+s] = (f32x4){EXP2RAW(al2[s]*sdt),EXP2RAW(al2[s+1]*sdt),
                                      EXP2RAW(al2[s+2]*sdt),EXP2RAW(al2[s+3]*sdt)};
  }
}

// scanB: 8-deep load prefetch (bit-identical ordering)
__global__ __launch_bounds__(256) void k_scanB(float* __restrict__ hend, const float* __restrict__ aprod){
  int i = blockIdx.x*256 + threadIdx.x;
  float H = 0.f;
  for (int k0 = 0; k0 < NCH; k0 += 8){
    float e[8], ap[8];
    #pragma unroll
    for (int j = 0; j < 8; j++){
      size_t o = (size_t)(k0+j)*DIM*16 + i;
      e[j] = hend[o]; ap[j] = aprod[o];
    }
    #pragma unroll
    for (int j = 0; j < 8; j++){
      size_t o = (size_t)(k0+j)*DIM*16 + i;
      hend[o] = H;
      H = e[j] + ap[j]*H;
    }
  }
}

// scanCorr: y[t] = (ylocal[t] + sum_s C[t][s]*Hin[s]*2^(al2[s]*cumdt[t])) * silu(z[t])
// Early-exit once 2^(alSlow*cum) < 2^-33; gate-only tail. 8-step register batching.
__global__ __launch_bounds__(256) void k_scanCorr(
    const unsigned short* __restrict__ delta, const unsigned short* __restrict__ xz,
    const float* __restrict__ dbc, const float* __restrict__ A_log,
    const float* __restrict__ hin, unsigned short* __restrict__ y)
{
  __shared__ float sC[CL][16];
  int tid = threadIdx.x;
  int c = blockIdx.x*256 + tid;
  int k = blockIdx.y;
  float al2[16];
  #pragma unroll
  for (int s = 0; s < 16; s++) al2[s] = -expf(A_log[(size_t)c*16 + s]) * LOG2E;
  bool fast = true;
  #pragma unroll
  for (int s = 1; s < 16; s++)
    fast = fast && (fabsf(al2[s] - (float)(s+1)*al2[0]) <= 1e-4f*fabsf(al2[s]));
  float alSlow = al2[0];
  #pragma unroll
  for (int s = 1; s < 16; s++) alSlow = fmaxf(alSlow, al2[s]);
  float Hin[16];
  size_t base = ((size_t)k*DIM + c)*16;
  #pragma unroll
  for (int s = 0; s < 16; s += 4){
    f32x4 v = *(const f32x4*)&hin[base+s];
    Hin[s] = v.x; Hin[s+1] = v.y; Hin[s+2] = v.z; Hin[s+3] = v.w;
  }
  for (int idx = tid; idx < CL*16; idx += 256){
    int t = idx >> 4, j = idx & 15;
    sC[t][j] = dbc[(size_t)(k*CL + t)*128 + 64 + j];
  }
  __syncthreads();
  const unsigned short* dp = delta + (size_t)k*CL*DIM + c;
  const unsigned short* zp = xz + (size_t)k*CL*3072 + 1536 + c;
  unsigned short* yp = y + (size_t)k*CL*DIM + c;
  float cum = 0.f;
  int t = 0;
  if (fast){
    bool done = false;
    for (int t0 = 0; t0 < CL && !done; t0 += 8){
      unsigned short dtb[8], zzb[8], ylb[8];
      #pragma unroll
      for (int j = 0; j < 8; j++){
        dtb[j] = dp[(t0+j)*DIM];
        zzb[j] = zp[(t0+j)*3072];
        ylb[j] = yp[(t0+j)*DIM];
      }
      #pragma unroll
      for (int j = 0; j < 8; j++){
        float dt = bf2f(dtb[j]);
        cum += dt;
        float e1 = EXP2RAW(cum*al2[0]);
        if (e1 < 0x1p-33f){ t = t0 + j; done = true; break; }
        float dA[16];
        pow_tree(e1, dA);
        f32x4 Cv[4];
        #pragma unroll
        for (int q = 0; q < 4; q++) Cv[q] = *(const f32x4*)&sC[t0+j][q*4];
        float ap[4] = {0.f,0.f,0.f,0.f};
        #pragma unroll
        for (int s = 0; s < 16; s++)
          ap[s>>2] += Hin[s]*dA[s]*Cv[s>>2][s&3];
        float corr = (ap[0]+ap[1]) + (ap[2]+ap[3]);
        float yl = bf2f(ylb[j]);
        float zz = bf2f(zzb[j]);
        yp[(t0+j)*DIM] = f2bf((yl + corr) * (zz * sigmoidf_(zz)));
      }
      if (!done) t = t0 + 8;
    }
  } else {
    for (; t < CL; t++){
      float dt = bf2f(dp[t*DIM]);
      cum += dt;
      if (EXP2RAW(cum*alSlow) < 0x1p-33f) break;
      f32x4 Cv[4];
      #pragma unroll
      for (int q = 0; q < 4; q++) Cv[q] = *(const f32x4*)&sC[t][q*4];
      float ap[4] = {0.f,0.f,0.f,0.f};
      #pragma unroll
      for (int s = 0; s < 16; s++)
        ap[s>>2] += Hin[s]*EXP2RAW(cum*al2[s])*Cv[s>>2][s&3];
      float corr = (ap[0]+ap[1]) + (ap[2]+ap[3]);
      float yl = bf2f(yp[t*DIM]);
      float zz = bf2f(zp[t*3072]);
      float yv = (yl + corr) * (zz * sigmoidf_(zz));
      yp[t*DIM] = f2bf(yv);
    }
  }
  // gate-only tail (batched)
  for (; t + 7 < CL; t += 8){
    unsigned short zzb[8], ylb[8];
    #pragma unroll
    for (int j = 0; j < 8; j++){
      ylb[j] = yp[(t+j)*DIM];
      zzb[j] = zp[(t+j)*3072];
    }
    #pragma unroll
    for (int j = 0; j < 8; j++){
      float yl = bf2f(ylb[j]);
      float zz = bf2f(zzb[j]);
      yp[(t+j)*DIM] = f2bf(yl * (zz * sigmoidf_(zz)));
    }
  }
  for (; t < CL; t++){
    float yl = bf2f(yp[t*DIM]);
    float zz = bf2f(zp[t*3072]);
    yp[t*DIM] = f2bf(yl * (zz * sigmoidf_(zz)));
  }
}

// ---------------- GCN aggregation (fp8 rows; HW cvt decode, 8-edge MLP unroll) ----------------
__global__ __launch_bounds__(192) void k_aggregate(
    const unsigned char* __restrict__ hq, const int* __restrict__ row_ptr,
    const int* __restrict__ csr_src, const float* __restrict__ normD,
    unsigned short* __restrict__ m)
{
  int d = blockIdx.x; int tid = threadIdx.x;
  int e0 = row_ptr[d], e1 = row_ptr[d+1];
  float a0 = 0.f, a1 = 0.f, a2 = 0.f, a3 = 0.f;
#if __has_builtin(__builtin_amdgcn_cvt_f32_fp8)
  int e = e0;
  for (; e + 7 < e1; e += 8){
    int sx[8];
    #pragma unroll
    for (int j = 0; j < 8; j++) sx[j] = csr_src[e+j];
    unsigned int w[8];
    #pragma unroll
    for (int j = 0; j < 8; j++) w[j] = *((const unsigned int*)(hq + (size_t)sx[j]*DF) + tid);
    a0 += (__builtin_amdgcn_cvt_f32_fp8(w[0], 0) + __builtin_amdgcn_cvt_f32_fp8(w[1], 0))
        + (__builtin_amdgcn_cvt_f32_fp8(w[2], 0) + __builtin_amdgcn_cvt_f32_fp8(w[3], 0));
    a1 += (__builtin_amdgcn_cvt_f32_fp8(w[0], 1) + __builtin_amdgcn_cvt_f32_fp8(w[1], 1))
        + (__builtin_amdgcn_cvt_f32_fp8(w[2], 1) + __builtin_amdgcn_cvt_f32_fp8(w[3], 1));
    a2 += (__builtin_amdgcn_cvt_f32_fp8(w[0], 2) + __builtin_amdgcn_cvt_f32_fp8(w[1], 2))
        + (__builtin_amdgcn_cvt_f32_fp8(w[2], 2) + __builtin_amdgcn_cvt_f32_fp8(w[3], 2));
    a3 += (__builtin_amdgcn_cvt_f32_fp8(w[0], 3) + __builtin_amdgcn_cvt_f32_fp8(w[1], 3))
        + (__builtin_amdgcn_cvt_f32_fp8(w[2], 3) + __builtin_amdgcn_cvt_f32_fp8(w[3], 3));
    a0 += (__builtin_amdgcn_cvt_f32_fp8(w[4], 0) + __builtin_amdgcn_cvt_f32_fp8(w[5], 0))
        + (__builtin_amdgcn_cvt_f32_fp8(w[6], 0) + __builtin_amdgcn_cvt_f32_fp8(w[7], 0));
    a1 += (__builtin_amdgcn_cvt_f32_fp8(w[4], 1) + __builtin_amdgcn_cvt_f32_fp8(w[5], 1))
        + (__builtin_amdgcn_cvt_f32_fp8(w[6], 1) + __builtin_amdgcn_cvt_f32_fp8(w[7], 1));
    a2 += (__builtin_amdgcn_cvt_f32_fp8(w[4], 2) + __builtin_amdgcn_cvt_f32_fp8(w[5], 2))
        + (__builtin_amdgcn_cvt_f32_fp8(w[6], 2) + __builtin_amdgcn_cvt_f32_fp8(w[7], 2));
    a3 += (__builtin_amdgcn_cvt_f32_fp8(w[4], 3) + __builtin_amdgcn_cvt_f32_fp8(w[5], 3))
        + (__builtin_amdgcn_cvt_f32_fp8(w[6], 3) + __builtin_amdgcn_cvt_f32_fp8(w[7], 3));
  }
  for (; e + 3 < e1; e += 4){
    int s0 = csr_src[e],   s1 = csr_src[e+1];
    int s2 = csr_src[e+2], s3 = csr_src[e+3];
    unsigned int w0 = *((const unsigned int*)(hq + (size_t)s0*DF) + tid);
    unsigned int w1 = *((const unsigned int*)(hq + (size_t)s1*DF) + tid);
    unsigned int w2 = *((const unsigned int*)(hq + (size_t)s2*DF) + tid);
    unsigned int w3 = *((const unsigned int*)(hq + (size_t)s3*DF) + tid);
    a0 += (__builtin_amdgcn_cvt_f32_fp8(w0, 0) + __builtin_amdgcn_cvt_f32_fp8(w1, 0))
        + (__builtin_amdgcn_cvt_f32_fp8(w2, 0) + __builtin_amdgcn_cvt_f32_fp8(w3, 0));
    a1 += (__builtin_amdgcn_cvt_f32_fp8(w0, 1) + __builtin_amdgcn_cvt_f32_fp8(w1, 1))
        + (__builtin_amdgcn_cvt_f32_fp8(w2, 1) + __builtin_amdgcn_cvt_f32_fp8(w3, 1));
    a2 += (__builtin_amdgcn_cvt_f32_fp8(w0, 2) + __builtin_amdgcn_cvt_f32_fp8(w1, 2))
        + (__builtin_amdgcn_cvt_f32_fp8(w2, 2) + __builtin_amdgcn_cvt_f32_fp8(w3, 2));
    a3 += (__builtin_amdgcn_cvt_f32_fp8(w0, 3) + __builtin_amdgcn_cvt_f32_fp8(w1, 3))
        + (__builtin_amdgcn_cvt_f32_fp8(w2, 3) + __builtin_amdgcn_cvt_f32_fp8(w3, 3));
  }
  for (; e < e1; e++){
    int s0 = csr_src[e];
    unsigned int w0 = *((const unsigned int*)(hq + (size_t)s0*DF) + tid);
    a0 += __builtin_amdgcn_cvt_f32_fp8(w0, 0);
    a1 += __builtin_amdgcn_cvt_f32_fp8(w0, 1);
    a2 += __builtin_amdgcn_cvt_f32_fp8(w0, 2);
    a3 += __builtin_amdgcn_cvt_f32_fp8(w0, 3);
  }
  float nd = normD[d] * (1.f/H8SCALE);   // HW decode yields true e4m3 value
#else
  for (int e = e0; e < e1; e++){
    int sI = csr_src[e];
    unsigned int w = *((const unsigned int*)(hq + (size_t)sI*DF) + tid);
    a0 += fp8bits(w & 255u);
    a1 += fp8bits((w >> 8) & 255u);
    a2 += fp8bits((w >> 16) & 255u);
    a3 += fp8bits(w >> 24);
  }
  float nd = normD[d] * 0x1p+114f;       // 2^120 decode scale / H8SCALE(=2^6)
#endif
  uint2 o;
  o.x = (unsigned int)f2bf(a0*nd) | ((unsigned int)f2bf(a1*nd) << 16);
  o.y = (unsigned int)f2bf(a2*nd) | ((unsigned int)f2bf(a3*nd) << 16);
  *((uint2*)(m + (size_t)d*DF) + tid) = o;
}

// ---------------- finals (causal + gfeat merged; gfeat 8-deep load batch) ----------------
__global__ __launch_bounds__(256) void k_final(const unsigned short* __restrict__ h,
                                               const float* __restrict__ W_c,
                                               const float* __restrict__ b_c,
                                               float* __restrict__ out){
  int b = blockIdx.x;
  if (b < 2048){
    int wv = threadIdx.x >> 6, lane = threadIdx.x & 63;
    int r = b*4 + wv;
    float s = 0.f;
    #pragma unroll
    for (int j = 0; j < 12; j++){
      int cidx = lane + 64*j;
      s += bf2f(h[(size_t)r*DF + cidx]) * W_c[cidx];
    }
    s += __shfl_xor(s, 32); s += __shfl_xor(s, 16); s += __shfl_xor(s, 8);
    s += __shfl_xor(s, 4);  s += __shfl_xor(s, 2);  s += __shfl_xor(s, 1);
    if (lane == 0){
      float a = s + b_c[0];
      float cz = 1.f/(1.f + expf(-a));   // precise libm for f32 output
      out[DF + r] = cz;
      out[DF + NN + r] = (cz > 0.7f) ? 1.f : 0.f;
    }
  } else {
    int g = b - 2048;                 // 0..767
    int col = (g % 3)*256 + threadIdx.x;
    int r0 = (g / 3)*32;              // 256 chunks x 32 rows
    float s = 0.f;
    for (int rb = 0; rb < 32; rb += 8){
      unsigned short hb[8];
      #pragma unroll
      for (int j = 0; j < 8; j++) hb[j] = h[(size_t)(r0+rb+j)*DF + col];
      #pragma unroll
      for (int j = 0; j < 8; j++) s += bf2f(hb[j]);
    }
    atomicAdd(&out[col], s * (1.f/8192.f));
  }
}

// ---------------- launch ----------------
extern "C" void kernel_launch(void* const* d_in, const int* in_sizes, int n_in,
                              void* d_out, int out_size, void* d_ws, size_t ws_size,
                              hipStream_t stream) {
  const float* node_feats = (const float*)d_in[0];
  const int*   timestamps = (const int*)d_in[1];
  const int*   ei         = (const int*)d_in[2];
  const int*   e_src = ei;
  const int*   e_dst = ei + NE_;
  const float* W_in    = (const float*)d_in[3];
  const float* conv_w  = (const float*)d_in[4];
  const float* conv_b  = (const float*)d_in[5];
  const float* W_xproj = (const float*)d_in[6];
  const float* W_dt    = (const float*)d_in[7];
  const float* b_dt    = (const float*)d_in[8];
  const float* A_log   = (const float*)d_in[9];
  const float* D_param = (const float*)d_in[10];
  const float* W_out   = (const float*)d_in[11];
  const float* Wg      = (const float*)d_in[12];
  const float* bg      = (const float*)d_in[13];
  const float* W_c     = (const float*)d_in[14];
  const float* b_c     = (const float*)d_in[15];
  float* out = (float*)d_out;

  char* ws = (char*)d_ws;
  size_t off = 0;
  auto alloc = [&](size_t bytes) -> char* {
    char* p = ws + off; off += (bytes + 255) & ~(size_t)255; return p;
  };
  unsigned short* WinT   = (unsigned short*)alloc((size_t)3072*768*2);
  unsigned short* WxT    = (unsigned short*)alloc((size_t)128*1536*2);
  unsigned short* WdtT   = (unsigned short*)alloc((size_t)1536*64*2);
  unsigned short* WoutT  = (unsigned short*)alloc((size_t)768*1536*2);
  unsigned short* WgT    = (unsigned short*)alloc((size_t)3*768*768*2);
  unsigned short* seq    = (unsigned short*)alloc((size_t)NN*DF*2);
  unsigned short* xz     = (unsigned short*)alloc((size_t)NN*3072*2);
  unsigned short* ubuf   = (unsigned short*)alloc((size_t)NN*DIM*2);
  float*          dbc    = (float*)alloc((size_t)NN*128*4);
  unsigned short* dt48   = (unsigned short*)alloc((size_t)NN*64*2);
  unsigned short* deltaB = (unsigned short*)alloc((size_t)NN*DIM*2);
  unsigned short* ybuf   = (unsigned short*)alloc((size_t)NN*DIM*2);
  unsigned short* hbuf   = (unsigned short*)alloc((size_t)NN*DF*2);
  unsigned short* mbuf   = (unsigned short*)alloc((size_t)NN*DF*2);
  unsigned char*  hq     = (unsigned char*)alloc((size_t)NN*DF);
  int*   pos    = (int*)alloc((size_t)NN*4);
  int*   degS   = (int*)alloc((size_t)2*NN*4);
  int*   degD   = degS + NN;
  float* normS  = (float*)alloc((size_t)NN*4);
  float* normD  = (float*)alloc((size_t)NN*4);
  int*   rowp   = (int*)alloc((size_t)(NN+1)*4);
  int*   cursor = (int*)alloc((size_t)NN*4);
  int*   csr    = (int*)alloc((size_t)NE_*4);

  // scan summaries: hend aliases seq (dead after G1); aprod aliases mbuf
  // (first written by k_aggregate, after scanB consumed aprod)
  float* hend  = (float*)seq;
  float* aprod = (float*)mbuf;

  // 1. weight prep (LDS-tiled transpose) + zero-init (pos/degS+degD/out[0:768])
  k_prep<<<1465, 256, 0, stream>>>(W_in, W_xproj, W_dt, W_out, Wg,
                                   WinT, WxT, WdtT, WoutT, WgT,
                                   pos, degS, out);
  // 2. rank + degree count
  k_rank_deg<<<2048, 256, 0, stream>>>(timestamps, pos, e_src, e_dst, degS, degD);
  // 3. norms + rowptr
  k_graphfix<<<9, 1024, 0, stream>>>(degS, degD, normS, normD, rowp, cursor);
  // 4. gather + csr fill
  k_scatter<<<NN + 1024, 256, 0, stream>>>(node_feats, pos, seq, e_src, e_dst, cursor, csr);

  // G1: xz = seq @ W_in
  k_gemm<0><<<64*24, 256, 0, stream>>>(seq, WinT, 3072, 768, 768, 768,
                                       nullptr, 0, xz, 3072, nullptr, nullptr, nullptr, nullptr);
  // conv + silu -> u (sliding-window)
  k_conv_silu<<<dim3(6, NN/CT), 256, 0, stream>>>(xz, conv_w, conv_b, ubuf);
  // G2: dbc = u @ W_xproj; also dt48
  k_gemm<1><<<64*1, 256, 0, stream>>>(ubuf, WxT, 128, 1536, 1536, 1536,
                                      dbc, 128, nullptr, 0, nullptr, dt48, nullptr, nullptr);
  // G3: delta = softplus(...) -> bf16
  k_gemm<2><<<64*12, 256, 0, stream>>>(dt48, WdtT, 1536, 64, 64, 64,
                                       nullptr, 0, deltaB, 1536, b_dt, nullptr, nullptr, nullptr);
  // scan: single sequential pass + combine + parallel correction
  k_scanA<<<dim3(DIM/256, NCH), 256, 0, stream>>>(deltaB, ubuf, dbc, A_log, D_param, hend, aprod, ybuf);
  k_scanB<<<96, 256, 0, stream>>>(hend, aprod);
  k_scanCorr<<<dim3(DIM/256, NCH), 256, 0, stream>>>(deltaB, xz, dbc, A_log, hend, ybuf);
  // G4: h = y @ W_out -> fp8 (normS-prescaled)
  k_gemm<5><<<64*6, 256, 0, stream>>>(ybuf, WoutT, 768, 1536, 1536, 1536,
                                      nullptr, 0, nullptr, 768, nullptr, nullptr, hq, normS);
  // 3 GCN layers
  k_aggregate<<<NN, 192, 0, stream>>>(hq, rowp, csr, normD, mbuf);
  k_gemm<4><<<64*6, 256, 0, stream>>>(mbuf, WgT, 768, 768, 768, 768,
                                      nullptr, 0, nullptr, 768, bg, nullptr, hq, normS);
  k_aggregate<<<NN, 192, 0, stream>>>(hq, rowp, csr, normD, mbuf);
  k_gemm<4><<<64*6, 256, 0, stream>>>(mbuf, WgT + (size_t)768*768, 768, 768, 768, 768,
                                      nullptr, 0, nullptr, 768, bg + 768, nullptr, hq, normS);
  k_aggregate<<<NN, 192, 0, stream>>>(hq, rowp, csr, normD, mbuf);
  k_gemm<3><<<64*6, 256, 0, stream>>>(mbuf, WgT + (size_t)2*768*768, 768, 768, 768, 768,
                                      nullptr, 0, hbuf, 768, bg + 2*768, nullptr, nullptr, nullptr);
  // finals (causal + graph_feat)
  k_final<<<2816, 256, 0, stream>>>(hbuf, W_c, b_c, out);
}

// Round 37
// 438.110 us; speedup vs baseline: 1.0792x; 1.0338x over previous
//
#include <hip/hip_runtime.h>
#include <math.h>

#define NN 8192
#define DF 768
#define NE_ 262144
#define DIM 1536
#define DSN 16
#define NCH 128
#define CL  64   // NN / NCH
#define CT  64   // conv time-block

typedef short short8 __attribute__((ext_vector_type(8)));
typedef float f32x4 __attribute__((ext_vector_type(4)));
typedef unsigned short us4 __attribute__((ext_vector_type(4)));

__device__ __forceinline__ float bf2f(unsigned short u){
  unsigned int v = ((unsigned int)u) << 16; float f; __builtin_memcpy(&f, &v, 4); return f;
}
__device__ __forceinline__ unsigned short f2bf(float f){
  unsigned int x; __builtin_memcpy(&x, &f, 4);
  x += 0x7fffu + ((x >> 16) & 1u);
  return (unsigned short)(x >> 16);
}
#define EXP2RAW(x) __builtin_amdgcn_exp2f(x)   // single v_exp_f32
#define LOG2E 1.44269504088896f
#define LN2   0.69314718055995f
#define H8SCALE 64.f
// fast sigmoid: native exp2 + rcp
__device__ __forceinline__ float sigmoidf_(float x){
  return 1.f/(1.f + EXP2RAW(-x*LOG2E));
}
// fast softplus: ln2 * log2(1 + 2^(v*log2e)); exact passthrough for large v
__device__ __forceinline__ float softplusf_(float v){
  if (v > 20.f) return v;
  return LN2 * __log2f(1.f + EXP2RAW(v*LOG2E));
}

// ---- fp8 e4m3fn encode ----
__device__ __forceinline__ unsigned char f2fp8(float v){
  float y = v * H8SCALE;
#if __has_builtin(__builtin_amdgcn_cvt_pk_fp8_f32)
  return (unsigned char)(__builtin_amdgcn_cvt_pk_fp8_f32(y, y, 0, false) & 0xff);
#else
  unsigned int u; __builtin_memcpy(&u, &y, 4);
  unsigned char s = (unsigned char)((u >> 24) & 0x80);
  float a = fabsf(y);
  if (a >= 448.f) return (unsigned char)(s | 0x7E);
  if (a < 0x1p-10f) return s;
  unsigned int ab = u & 0x7fffffffu;
  int ef = (int)(ab >> 23) - 127;
  int qe = ef - 3; if (qe < -9) qe = -9;
  float q; { unsigned int qb = (unsigned int)(qe + 127) << 23; __builtin_memcpy(&q, &qb, 4); }
  float n = rintf(a / q);
  float m = n * q;
  unsigned int mb; __builtin_memcpy(&mb, &m, 4);
  int E = (int)(mb >> 23) - 127 + 7;
  unsigned char out;
  if (E <= 0) out = (unsigned char)rintf(m * 512.f);
  else        out = (unsigned char)((E << 3) | ((mb >> 20) & 7));
  return (unsigned char)(s | out);
#endif
}
// software decode bit-trick: result = e4m3(b) * 2^-120 (exact); caller folds 2^120.
__device__ __forceinline__ float fp8bits(unsigned int b){
  unsigned int t = ((b & 0x80u) << 24) | ((b & 0x7fu) << 20);
  float f; __builtin_memcpy(&f, &t, 4); return f;
}

// async global->LDS, 16B per lane
__device__ __forceinline__ void gl_lds16(const unsigned short* g, unsigned short* l){
  __builtin_amdgcn_global_load_lds(
      (const __attribute__((address_space(1))) unsigned int*)g,
      (__attribute__((address_space(3))) unsigned int*)l,
      16, 0, 0);
}

// ---------------- weight prep: LDS-tiled transpose (coalesced both sides) ----------------
__global__ __launch_bounds__(256) void k_prep(
    const float* __restrict__ W_in, const float* __restrict__ W_xproj,
    const float* __restrict__ W_dt, const float* __restrict__ W_out,
    const float* __restrict__ Wg,
    unsigned short* __restrict__ WinT, unsigned short* __restrict__ WxT,
    unsigned short* __restrict__ WdtT, unsigned short* __restrict__ WoutT,
    unsigned short* __restrict__ WgT,
    int* __restrict__ pos, int* __restrict__ degS, float* __restrict__ outv)
{
  int b = blockIdx.x;
  int tid = threadIdx.x;
  if (b >= 1368){
    if (b < 1400)       pos[(b-1368)*256 + tid] = 0;
    else if (b < 1464)  degS[(b-1400)*256 + tid] = 0;   // degS+degD contiguous 2*NN
    else { outv[tid] = 0.f; outv[256+tid] = 0.f; outv[512+tid] = 0.f; }
    return;
  }
  // decode matrix + tile
  const float* in; unsigned short* out; int K, N, Kp, Np, kt, nt;
  if (b < 576){        in = W_in;    out = WinT;  K = 768;  N = 3072; Kp = 768;  Np = 3072;
                       kt = b / 48;  nt = b % 48; }
  else if (b < 624){   int l = b - 576;
                       in = W_xproj; out = WxT;   K = 1536; N = 80;   Kp = 1536; Np = 128;
                       kt = l >> 1;  nt = l & 1; }
  else if (b < 648){   int l = b - 624;
                       in = W_dt;    out = WdtT;  K = 48;   N = 1536; Kp = 64;   Np = 1536;
                       kt = 0;       nt = l; }
  else if (b < 936){   int l = b - 648;
                       in = W_out;   out = WoutT; K = 1536; N = 768;  Kp = 1536; Np = 768;
                       kt = l / 12;  nt = l % 12; }
  else {               int l = b - 936;
                       int g = l / 144; int r = l % 144;
                       in = Wg + (size_t)g*768*768; out = WgT + (size_t)g*768*768;
                       K = 768; N = 768; Kp = 768; Np = 768;
                       kt = r / 12;  nt = r % 12; }
  int k0 = kt*64, n0 = nt*64;
  __shared__ float tl[64][65];
  int ln = tid & 63;   // inner (contiguous) index
  int lk = tid >> 6;   // 0..3
  #pragma unroll
  for (int kk = lk; kk < 64; kk += 4){
    int gk = k0 + kk, gn = n0 + ln;
    float v = (gk < K && gn < N) ? in[(size_t)gk*N + gn] : 0.f;
    tl[kk][ln] = v;
  }
  __syncthreads();
  #pragma unroll
  for (int nn = lk; nn < 64; nn += 4){
    int gn2 = n0 + nn, gk2 = k0 + ln;
    if (gn2 < Np && gk2 < Kp)
      out[(size_t)gn2*Kp + gk2] = f2bf(tl[ln][nn]);
  }
}

// ---------------- rank + deg_count (merged) ----------------
__global__ __launch_bounds__(256) void k_rank_deg(const int* __restrict__ ts, int* __restrict__ pos,
                                                  const int* __restrict__ esrc, const int* __restrict__ edst,
                                                  int* __restrict__ degS, int* __restrict__ degD){
  int b = blockIdx.x;
  if (b < 1024){
    __shared__ int sT[256];
    int ic = b & 31, jc = b >> 5;
    int i = ic*256 + threadIdx.x;
    int my = ts[i];
    int c0 = jc*256;
    sT[threadIdx.x] = ts[c0 + threadIdx.x];
    __syncthreads();
    int r = 0;
    #pragma unroll 8
    for (int j = 0; j < 256; j++){
      int t = sT[j]; int jj = c0 + j;
      r += (t < my || (t == my && jj < i)) ? 1 : 0;
    }
    atomicAdd(&pos[i], r);
  } else {
    int e = (b-1024)*256 + threadIdx.x;
    atomicAdd(&degS[esrc[e]], 1); atomicAdd(&degD[edst[e]], 1);
  }
}

// ---------------- norms + rowptr (merged; 1024 threads) ----------------
__global__ __launch_bounds__(1024) void k_graphfix(const int* __restrict__ degS, const int* __restrict__ degD,
                                                   float* __restrict__ normS, float* __restrict__ normD,
                                                   int* __restrict__ row_ptr, int* __restrict__ cursor){
  int b = blockIdx.x;
  int tid = threadIdx.x;
  if (b < 8){
    int i = b*1024 + tid;
    normS[i] = rsqrtf(fmaxf((float)degS[i], 1.f));
    normD[i] = rsqrtf(fmaxf((float)degD[i], 1.f));
    return;
  }
  __shared__ int sp[1024];
  int base = tid*8;
  int loc[8]; int s = 0;
  #pragma unroll
  for (int j = 0; j < 8; j++){ loc[j] = degD[base+j]; s += loc[j]; }
  sp[tid] = s; __syncthreads();
  for (int o = 1; o < 1024; o <<= 1){
    int v = (tid >= o) ? sp[tid-o] : 0; __syncthreads();
    sp[tid] += v; __syncthreads();
  }
  int run = sp[tid] - s;
  #pragma unroll
  for (int j = 0; j < 8; j++){ row_ptr[base+j] = run; cursor[base+j] = run; run += loc[j]; }
  if (tid == 1023) row_ptr[NN] = sp[1023];
}

// ---------------- gather + csr_fill (merged; vectorized row copy) ----------------
__global__ __launch_bounds__(256) void k_scatter(const float* __restrict__ nf, const int* __restrict__ pos,
                                                 unsigned short* __restrict__ seq,
                                                 const int* __restrict__ esrc, const int* __restrict__ edst,
                                                 int* __restrict__ cursor, int* __restrict__ csr_src){
  int b = blockIdx.x;
  if (b < NN){
    int p = pos[b];
    const float* src = nf + (size_t)b*DF;
    unsigned short* dst = seq + (size_t)p*DF;
    for (int j = threadIdx.x; j < DF/4; j += 256){
      f32x4 v = *(const f32x4*)&src[j*4];
      us4 o = { f2bf(v.x), f2bf(v.y), f2bf(v.z), f2bf(v.w) };
      *(us4*)&dst[j*4] = o;
    }
  } else {
    int e = (b-NN)*256 + threadIdx.x;
    int d = edst[e];
    int p = atomicAdd(&cursor[d], 1);
    csr_src[p] = esrc[e];
  }
}

// ---------------- bf16 MFMA GEMM (128x128 tile, BK=32 ping-pong prefetch, 4 waves) ----------------
// T3 minimum-2-phase: issue STAGE(next 32 cols) before compute(cur) so global->LDS
// latency hides under ds_read+MFMA; one barrier per 32-K step (same density as before).
// MFMA order over k unchanged -> bit-identical accumulation.
// XCD-chunked blockIdx swizzle (T1). EPI: 0 bf16; 1 f32+dt48; 2 softplus bf16;
// 3 gelu bf16; 4 gelu*normS fp8; 5 v*normS fp8
template<int EPI>
__global__ __launch_bounds__(256) void k_gemm(
    const unsigned short* __restrict__ A, const unsigned short* __restrict__ B,
    int N, int K, int lda, int ldb,
    float* __restrict__ outF, int ldoF,
    unsigned short* __restrict__ outB, int ldoB,
    const float* __restrict__ bias,
    unsigned short* __restrict__ out2,
    unsigned char* __restrict__ outQ,
    const float* __restrict__ nrmS)
{
  __shared__ unsigned short sA[2][128*32];
  __shared__ unsigned short sB[2][128*32];
  int tid = threadIdx.x;
  int tnc = N >> 7;
  int nwg = gridDim.x;
  int bid = blockIdx.x;
  int swz = (nwg & 7) ? bid : ((bid & 7)*(nwg >> 3) + (bid >> 3));
  int bm = (swz / tnc) << 7;
  int bn = (swz % tnc) << 7;
  int wv = tid >> 6, lane = tid & 63;
  int wm = wv >> 1, wn = wv & 1;
  int l15 = lane & 15, l4 = lane >> 4;

  f32x4 acc[4][4];
  #pragma unroll
  for (int i = 0; i < 4; i++)
    #pragma unroll
    for (int j = 0; j < 4; j++)
      acc[i][j] = (f32x4){0.f,0.f,0.f,0.f};

  int r0 = (wv*2)*16 + (lane >> 2);
  int r1 = r0 + 16;
  int cc = (lane & 3)*8;
  const unsigned short* gA0 = A + (size_t)(bm + r0)*lda + cc;
  const unsigned short* gA1 = A + (size_t)(bm + r1)*lda + cc;
  const unsigned short* gB0 = B + (size_t)(bn + r0)*ldb + cc;
  const unsigned short* gB1 = B + (size_t)(bn + r1)*ldb + cc;
  unsigned short* bufA[2] = { &sA[0][(size_t)(wv*2)*512], &sA[1][(size_t)(wv*2)*512] };
  unsigned short* bufB[2] = { &sB[0][(size_t)(wv*2)*512], &sB[1][(size_t)(wv*2)*512] };

  // prologue: stage k-cols [0,32) into buffer 0
  gl_lds16(gA0, bufA[0]);
  gl_lds16(gA1, bufA[0] + 512);
  gl_lds16(gB0, bufB[0]);
  gl_lds16(gB1, bufB[0] + 512);
  __syncthreads();

  int nk = K >> 5;   // number of 32-wide K steps
  int cur = 0;
  for (int ks = 0; ks < nk; ks++){
    int nxt = cur ^ 1;
    if (ks + 1 < nk){
      int kc = (ks + 1) << 5;
      gl_lds16(gA0 + kc, bufA[nxt]);
      gl_lds16(gA1 + kc, bufA[nxt] + 512);
      gl_lds16(gB0 + kc, bufB[nxt]);
      gl_lds16(gB1 + kc, bufB[nxt] + 512);
    }
    short8 af[4], bf_[4];
    #pragma unroll
    for (int i = 0; i < 4; i++){
      af[i]  = *(const short8*)&sA[cur][(wm*64 + i*16 + l15)*32 + l4*8];
      bf_[i] = *(const short8*)&sB[cur][(wn*64 + i*16 + l15)*32 + l4*8];
    }
    #pragma unroll
    for (int i = 0; i < 4; i++)
      #pragma unroll
      for (int j = 0; j < 4; j++)
        acc[i][j] = __builtin_amdgcn_mfma_f32_16x16x32_bf16(af[i], bf_[j], acc[i][j], 0, 0, 0);
    __syncthreads();   // drains prefetch (vmcnt) + guards cur-buffer reuse
    cur = nxt;
  }

  #pragma unroll
  for (int i = 0; i < 4; i++)
    #pragma unroll
    for (int j = 0; j < 4; j++)
      #pragma unroll
      for (int rr = 0; rr < 4; rr++){
        int row = bm + wm*64 + i*16 + l4*4 + rr;
        int col = bn + wn*64 + j*16 + l15;
        float v = acc[i][j][rr];
        if (EPI == 0){
          outB[(size_t)row*ldoB + col] = f2bf(v);
        } else if (EPI == 1){
          outF[(size_t)row*ldoF + col] = v;
          if (col < 64) out2[(size_t)row*64 + col] = (col < 48) ? f2bf(v) : (unsigned short)0;
        } else if (EPI == 2){
          outB[(size_t)row*ldoB + col] = f2bf(softplusf_(v + bias[col]));
        } else if (EPI == 3){
          v += bias[col];
          float g = 0.5f*v*(1.f + erff(v*0.70710678118f));
          outB[(size_t)row*ldoB + col] = f2bf(g);
        } else if (EPI == 4){
          v += bias[col];
          float g = 0.5f*v*(1.f + erff(v*0.70710678118f));
          outQ[(size_t)row*ldoB + col] = f2fp8(g * nrmS[row]);
        } else {
          outQ[(size_t)row*ldoB + col] = f2fp8(v * nrmS[row]);
        }
      }
}

// ---------------- causal conv + silu: sliding window, 8-wide load batch ----------------
__global__ __launch_bounds__(256) void k_conv_silu(const unsigned short* __restrict__ xz,
                                                   const float* __restrict__ conv_w,
                                                   const float* __restrict__ conv_b,
                                                   unsigned short* __restrict__ u){
  int c = blockIdx.x*256 + threadIdx.x;   // 0..1535
  int t0 = blockIdx.y*CT;
  float w0 = conv_w[c*4], w1 = conv_w[c*4+1], w2 = conv_w[c*4+2], w3 = conv_w[c*4+3];
  float bb = conv_b[c];
  const unsigned short* xp = xz + c;      // column base, row stride 3072
  float x0 = (t0 >= 3) ? bf2f(xp[(size_t)(t0-3)*3072]) : 0.f;
  float x1 = (t0 >= 2) ? bf2f(xp[(size_t)(t0-2)*3072]) : 0.f;
  float x2 = (t0 >= 1) ? bf2f(xp[(size_t)(t0-1)*3072]) : 0.f;
  unsigned short* up = u + (size_t)t0*DIM + c;
  for (int r0 = 0; r0 < CT; r0 += 8){
    unsigned short xb[8];
    #pragma unroll
    for (int j = 0; j < 8; j++) xb[j] = xp[(size_t)(t0+r0+j)*3072];
    #pragma unroll
    for (int j = 0; j < 8; j++){
      float x3 = bf2f(xb[j]);
      float acc = bb + x0*w0 + x1*w1 + x2*w2 + x3*w3;
      up[(r0+j)*DIM] = f2bf(acc * sigmoidf_(acc));
      x0 = x1; x1 = x2; x2 = x3;
    }
  }
}

// ---------------- selective scan: single sequential pass + parallel correction ----------------
__device__ __forceinline__ void pow_tree(float e1, float dA[16]){
  float e2 = e1*e1, e4 = e2*e2, e8 = e4*e4;
  dA[0]=e1;      dA[1]=e2;      dA[2]=e2*e1;   dA[3]=e4;
  dA[4]=e4*e1;   dA[5]=e4*e2;   dA[6]=e4*dA[2];dA[7]=e8;
  dA[8]=e8*e1;   dA[9]=e8*e2;   dA[10]=e8*dA[2];dA[11]=e8*e4;
  dA[12]=e8*dA[4];dA[13]=e8*dA[5];dA[14]=e8*dA[6];dA[15]=e8*e8;
}

// scanA': local recurrence + C-dot; stores pre-gate ylocal (bf16), hend, aprod
__global__ __launch_bounds__(256) void k_scanA(
    const unsigned short* __restrict__ delta, const unsigned short* __restrict__ u,
    const float* __restrict__ dbc, const float* __restrict__ A_log,
    const float* __restrict__ D_param,
    float* __restrict__ hend, float* __restrict__ aprod,
    unsigned short* __restrict__ ylocal)
{
  __shared__ float sBC[CL][32];
  int tid = threadIdx.x;
  int c = blockIdx.x*256 + tid;
  int k = blockIdx.y;
  float al2[16];
  #pragma unroll
  for (int s = 0; s < 16; s++) al2[s] = -expf(A_log[(size_t)c*16 + s]) * LOG2E;
  bool fast = true;
  #pragma unroll
  for (int s = 1; s < 16; s++)
    fast = fast && (fabsf(al2[s] - (float)(s+1)*al2[0]) <= 1e-4f*fabsf(al2[s]));
  float Dc = D_param[c];
  float h[16];
  #pragma unroll
  for (int s = 0; s < 16; s++) h[s] = 0.f;
  float sdt = 0.f;
  for (int idx = tid; idx < CL*32; idx += 256){
    int t = idx >> 5, j = idx & 31;
    sBC[t][j] = dbc[(size_t)(k*CL + t)*128 + 48 + j];
  }
  __syncthreads();
  const unsigned short* dp = delta + (size_t)k*CL*DIM + c;
  const unsigned short* up = u + (size_t)k*CL*DIM + c;
  unsigned short* yp = ylocal + (size_t)k*CL*DIM + c;
  if (fast){
    for (int t0 = 0; t0 < CL; t0 += 8){
      unsigned short dtb[8], uub[8];
      #pragma unroll
      for (int j = 0; j < 8; j++){
        dtb[j] = dp[(t0+j)*DIM];
        uub[j] = up[(t0+j)*DIM];
      }
      #pragma unroll
      for (int j = 0; j < 8; j++){
        int t = t0 + j;
        float dt = bf2f(dtb[j]), uu = bf2f(uub[j]);
        f32x4 Bv[4], Cv[4];
        #pragma unroll
        for (int q = 0; q < 4; q++){
          Bv[q] = *(const f32x4*)&sBC[t][q*4];
          Cv[q] = *(const f32x4*)&sBC[t][16 + q*4];
        }
        float dtu = dt*uu;
        sdt += dt;
        float dA[16];
        pow_tree(EXP2RAW(dt*al2[0]), dA);
        float ap[4] = {0.f,0.f,0.f,0.f};
        #pragma unroll
        for (int s = 0; s < 16; s++){
          h[s] = h[s]*dA[s] + dtu*Bv[s>>2][s&3];
          ap[s>>2] += h[s]*Cv[s>>2][s&3];
        }
        float accv = (ap[0]+ap[1]) + (ap[2]+ap[3]);
        yp[t*DIM] = f2bf(accv + uu*Dc);      // pre-gate local y
      }
    }
  } else {
    unsigned short dtn = dp[0], uun = up[0];
    #pragma unroll 2
    for (int t = 0; t < CL; t++){
      float dt = bf2f(dtn), uu = bf2f(uun);
      int tn = (t+1 < CL) ? t+1 : t;
      dtn = dp[tn*DIM]; uun = up[tn*DIM];
      f32x4 Bv[4], Cv[4];
      #pragma unroll
      for (int q = 0; q < 4; q++){
        Bv[q] = *(const f32x4*)&sBC[t][q*4];
        Cv[q] = *(const f32x4*)&sBC[t][16 + q*4];
      }
      float dtu = dt*uu;
      sdt += dt;
      float ap[4] = {0.f,0.f,0.f,0.f};
      #pragma unroll
      for (int s = 0; s < 16; s++){
        float dA = EXP2RAW(dt*al2[s]);
        h[s] = h[s]*dA + dtu*Bv[s>>2][s&3];
        ap[s>>2] += h[s]*Cv[s>>2][s&3];
      }
      float accv = (ap[0]+ap[1]) + (ap[2]+ap[3]);
      yp[t*DIM] = f2bf(accv + uu*Dc);
    }
  }
  size_t base = ((size_t)k*DIM + c)*16;
  #pragma unroll
  for (int s = 0; s < 16; s += 4){
    *(f32x4*)&hend[base+s]  = (f32x4){h[s],h[s+1],h[s+2],h[s+3]};
    *(f32x4*)&aprod[base+s] = (f32x4){EXP2RAW(al2[s]*sdt),EXP2RAW(al2[s+1]*sdt),
                                      EXP2RAW(al2[s+2]*sdt),EXP2RAW(al2[s+3]*sdt)};
  }
}

// scanB: 8-deep load prefetch (bit-identical ordering)
__global__ __launch_bounds__(256) void k_scanB(float* __restrict__ hend, const float* __restrict__ aprod){
  int i = blockIdx.x*256 + threadIdx.x;
  float H = 0.f;
  for (int k0 = 0; k0 < NCH; k0 += 8){
    float e[8], ap[8];
    #pragma unroll
    for (int j = 0; j < 8; j++){
      size_t o = (size_t)(k0+j)*DIM*16 + i;
      e[j] = hend[o]; ap[j] = aprod[o];
    }
    #pragma unroll
    for (int j = 0; j < 8; j++){
      size_t o = (size_t)(k0+j)*DIM*16 + i;
      hend[o] = H;
      H = e[j] + ap[j]*H;
    }
  }
}

// scanCorr: y[t] = (ylocal[t] + sum_s C[t][s]*Hin[s]*2^(al2[s]*cumdt[t])) * silu(z[t])
// Early-exit once 2^(alSlow*cum) < 2^-33; gate-only tail. 8-step register batching.
__global__ __launch_bounds__(256) void k_scanCorr(
    const unsigned short* __restrict__ delta, const unsigned short* __restrict__ xz,
    const float* __restrict__ dbc, const float* __restrict__ A_log,
    const float* __restrict__ hin, unsigned short* __restrict__ y)
{
  __shared__ float sC[CL][16];
  int tid = threadIdx.x;
  int c = blockIdx.x*256 + tid;
  int k = blockIdx.y;
  float al2[16];
  #pragma unroll
  for (int s = 0; s < 16; s++) al2[s] = -expf(A_log[(size_t)c*16 + s]) * LOG2E;
  bool fast = true;
  #pragma unroll
  for (int s = 1; s < 16; s++)
    fast = fast && (fabsf(al2[s] - (float)(s+1)*al2[0]) <= 1e-4f*fabsf(al2[s]));
  float alSlow = al2[0];
  #pragma unroll
  for (int s = 1; s < 16; s++) alSlow = fmaxf(alSlow, al2[s]);
  float Hin[16];
  size_t base = ((size_t)k*DIM + c)*16;
  #pragma unroll
  for (int s = 0; s < 16; s += 4){
    f32x4 v = *(const f32x4*)&hin[base+s];
    Hin[s] = v.x; Hin[s+1] = v.y; Hin[s+2] = v.z; Hin[s+3] = v.w;
  }
  for (int idx = tid; idx < CL*16; idx += 256){
    int t = idx >> 4, j = idx & 15;
    sC[t][j] = dbc[(size_t)(k*CL + t)*128 + 64 + j];
  }
  __syncthreads();
  const unsigned short* dp = delta + (size_t)k*CL*DIM + c;
  const unsigned short* zp = xz + (size_t)k*CL*3072 + 1536 + c;
  unsigned short* yp = y + (size_t)k*CL*DIM + c;
  float cum = 0.f;
  int t = 0;
  if (fast){
    bool done = false;
    for (int t0 = 0; t0 < CL && !done; t0 += 8){
      unsigned short dtb[8], zzb[8], ylb[8];
      #pragma unroll
      for (int j = 0; j < 8; j++){
        dtb[j] = dp[(t0+j)*DIM];
        zzb[j] = zp[(t0+j)*3072];
        ylb[j] = yp[(t0+j)*DIM];
      }
      #pragma unroll
      for (int j = 0; j < 8; j++){
        float dt = bf2f(dtb[j]);
        cum += dt;
        float e1 = EXP2RAW(cum*al2[0]);
        if (e1 < 0x1p-33f){ t = t0 + j; done = true; break; }
        float dA[16];
        pow_tree(e1, dA);
        f32x4 Cv[4];
        #pragma unroll
        for (int q = 0; q < 4; q++) Cv[q] = *(const f32x4*)&sC[t0+j][q*4];
        float ap[4] = {0.f,0.f,0.f,0.f};
        #pragma unroll
        for (int s = 0; s < 16; s++)
          ap[s>>2] += Hin[s]*dA[s]*Cv[s>>2][s&3];
        float corr = (ap[0]+ap[1]) + (ap[2]+ap[3]);
        float yl = bf2f(ylb[j]);
        float zz = bf2f(zzb[j]);
        yp[(t0+j)*DIM] = f2bf((yl + corr) * (zz * sigmoidf_(zz)));
      }
      if (!done) t = t0 + 8;
    }
  } else {
    for (; t < CL; t++){
      float dt = bf2f(dp[t*DIM]);
      cum += dt;
      if (EXP2RAW(cum*alSlow) < 0x1p-33f) break;
      f32x4 Cv[4];
      #pragma unroll
      for (int q = 0; q < 4; q++) Cv[q] = *(const f32x4*)&sC[t][q*4];
      float ap[4] = {0.f,0.f,0.f,0.f};
      #pragma unroll
      for (int s = 0; s < 16; s++)
        ap[s>>2] += Hin[s]*EXP2RAW(cum*al2[s])*Cv[s>>2][s&3];
      float corr = (ap[0]+ap[1]) + (ap[2]+ap[3]);
      float yl = bf2f(yp[t*DIM]);
      float zz = bf2f(zp[t*3072]);
      float yv = (yl + corr) * (zz * sigmoidf_(zz));
      yp[t*DIM] = f2bf(yv);
    }
  }
  // gate-only tail (batched)
  for (; t + 7 < CL; t += 8){
    unsigned short zzb[8], ylb[8];
    #pragma unroll
    for (int j = 0; j < 8; j++){
      ylb[j] = yp[(t+j)*DIM];
      zzb[j] = zp[(t+j)*3072];
    }
    #pragma unroll
    for (int j = 0; j < 8; j++){
      float yl = bf2f(ylb[j]);
      float zz = bf2f(zzb[j]);
      yp[(t+j)*DIM] = f2bf(yl * (zz * sigmoidf_(zz)));
    }
  }
  for (; t < CL; t++){
    float yl = bf2f(yp[t*DIM]);
    float zz = bf2f(zp[t*3072]);
    yp[t*DIM] = f2bf(yl * (zz * sigmoidf_(zz)));
  }
}

// ---------------- GCN aggregation (fp8 rows; HW cvt decode, 8-edge MLP unroll) ----------------
__global__ __launch_bounds__(192) void k_aggregate(
    const unsigned char* __restrict__ hq, const int* __restrict__ row_ptr,
    const int* __restrict__ csr_src, const float* __restrict__ normD,
    unsigned short* __restrict__ m)
{
  int d = blockIdx.x; int tid = threadIdx.x;
  int e0 = row_ptr[d], e1 = row_ptr[d+1];
  float a0 = 0.f, a1 = 0.f, a2 = 0.f, a3 = 0.f;
#if __has_builtin(__builtin_amdgcn_cvt_f32_fp8)
  int e = e0;
  for (; e + 7 < e1; e += 8){
    int sx[8];
    #pragma unroll
    for (int j = 0; j < 8; j++) sx[j] = csr_src[e+j];
    unsigned int w[8];
    #pragma unroll
    for (int j = 0; j < 8; j++) w[j] = *((const unsigned int*)(hq + (size_t)sx[j]*DF) + tid);
    a0 += (__builtin_amdgcn_cvt_f32_fp8(w[0], 0) + __builtin_amdgcn_cvt_f32_fp8(w[1], 0))
        + (__builtin_amdgcn_cvt_f32_fp8(w[2], 0) + __builtin_amdgcn_cvt_f32_fp8(w[3], 0));
    a1 += (__builtin_amdgcn_cvt_f32_fp8(w[0], 1) + __builtin_amdgcn_cvt_f32_fp8(w[1], 1))
        + (__builtin_amdgcn_cvt_f32_fp8(w[2], 1) + __builtin_amdgcn_cvt_f32_fp8(w[3], 1));
    a2 += (__builtin_amdgcn_cvt_f32_fp8(w[0], 2) + __builtin_amdgcn_cvt_f32_fp8(w[1], 2))
        + (__builtin_amdgcn_cvt_f32_fp8(w[2], 2) + __builtin_amdgcn_cvt_f32_fp8(w[3], 2));
    a3 += (__builtin_amdgcn_cvt_f32_fp8(w[0], 3) + __builtin_amdgcn_cvt_f32_fp8(w[1], 3))
        + (__builtin_amdgcn_cvt_f32_fp8(w[2], 3) + __builtin_amdgcn_cvt_f32_fp8(w[3], 3));
    a0 += (__builtin_amdgcn_cvt_f32_fp8(w[4], 0) + __builtin_amdgcn_cvt_f32_fp8(w[5], 0))
        + (__builtin_amdgcn_cvt_f32_fp8(w[6], 0) + __builtin_amdgcn_cvt_f32_fp8(w[7], 0));
    a1 += (__builtin_amdgcn_cvt_f32_fp8(w[4], 1) + __builtin_amdgcn_cvt_f32_fp8(w[5], 1))
        + (__builtin_amdgcn_cvt_f32_fp8(w[6], 1) + __builtin_amdgcn_cvt_f32_fp8(w[7], 1));
    a2 += (__builtin_amdgcn_cvt_f32_fp8(w[4], 2) + __builtin_amdgcn_cvt_f32_fp8(w[5], 2))
        + (__builtin_amdgcn_cvt_f32_fp8(w[6], 2) + __builtin_amdgcn_cvt_f32_fp8(w[7], 2));
    a3 += (__builtin_amdgcn_cvt_f32_fp8(w[4], 3) + __builtin_amdgcn_cvt_f32_fp8(w[5], 3))
        + (__builtin_amdgcn_cvt_f32_fp8(w[6], 3) + __builtin_amdgcn_cvt_f32_fp8(w[7], 3));
  }
  for (; e + 3 < e1; e += 4){
    int s0 = csr_src[e],   s1 = csr_src[e+1];
    int s2 = csr_src[e+2], s3 = csr_src[e+3];
    unsigned int w0 = *((const unsigned int*)(hq + (size_t)s0*DF) + tid);
    unsigned int w1 = *((const unsigned int*)(hq + (size_t)s1*DF) + tid);
    unsigned int w2 = *((const unsigned int*)(hq + (size_t)s2*DF) + tid);
    unsigned int w3 = *((const unsigned int*)(hq + (size_t)s3*DF) + tid);
    a0 += (__builtin_amdgcn_cvt_f32_fp8(w0, 0) + __builtin_amdgcn_cvt_f32_fp8(w1, 0))
        + (__builtin_amdgcn_cvt_f32_fp8(w2, 0) + __builtin_amdgcn_cvt_f32_fp8(w3, 0));
    a1 += (__builtin_amdgcn_cvt_f32_fp8(w0, 1) + __builtin_amdgcn_cvt_f32_fp8(w1, 1))
        + (__builtin_amdgcn_cvt_f32_fp8(w2, 1) + __builtin_amdgcn_cvt_f32_fp8(w3, 1));
    a2 += (__builtin_amdgcn_cvt_f32_fp8(w0, 2) + __builtin_amdgcn_cvt_f32_fp8(w1, 2))
        + (__builtin_amdgcn_cvt_f32_fp8(w2, 2) + __builtin_amdgcn_cvt_f32_fp8(w3, 2));
    a3 += (__builtin_amdgcn_cvt_f32_fp8(w0, 3) + __builtin_amdgcn_cvt_f32_fp8(w1, 3))
        + (__builtin_amdgcn_cvt_f32_fp8(w2, 3) + __builtin_amdgcn_cvt_f32_fp8(w3, 3));
  }
  for (; e < e1; e++){
    int s0 = csr_src[e];
    unsigned int w0 = *((const unsigned int*)(hq + (size_t)s0*DF) + tid);
    a0 += __builtin_amdgcn_cvt_f32_fp8(w0, 0);
    a1 += __builtin_amdgcn_cvt_f32_fp8(w0, 1);
    a2 += __builtin_amdgcn_cvt_f32_fp8(w0, 2);
    a3 += __builtin_amdgcn_cvt_f32_fp8(w0, 3);
  }
  float nd = normD[d] * (1.f/H8SCALE);   // HW decode yields true e4m3 value
#else
  for (int e = e0; e < e1; e++){
    int sI = csr_src[e];
    unsigned int w = *((const unsigned int*)(hq + (size_t)sI*DF) + tid);
    a0 += fp8bits(w & 255u);
    a1 += fp8bits((w >> 8) & 255u);
    a2 += fp8bits((w >> 16) & 255u);
    a3 += fp8bits(w >> 24);
  }
  float nd = normD[d] * 0x1p+114f;       // 2^120 decode scale / H8SCALE(=2^6)
#endif
  uint2 o;
  o.x = (unsigned int)f2bf(a0*nd) | ((unsigned int)f2bf(a1*nd) << 16);
  o.y = (unsigned int)f2bf(a2*nd) | ((unsigned int)f2bf(a3*nd) << 16);
  *((uint2*)(m + (size_t)d*DF) + tid) = o;
}

// ---------------- finals (causal + gfeat merged; gfeat 8-deep load batch) ----------------
__global__ __launch_bounds__(256) void k_final(const unsigned short* __restrict__ h,
                                               const float* __restrict__ W_c,
                                               const float* __restrict__ b_c,
                                               float* __restrict__ out){
  int b = blockIdx.x;
  if (b < 2048){
    int wv = threadIdx.x >> 6, lane = threadIdx.x & 63;
    int r = b*4 + wv;
    float s = 0.f;
    #pragma unroll
    for (int j = 0; j < 12; j++){
      int cidx = lane + 64*j;
      s += bf2f(h[(size_t)r*DF + cidx]) * W_c[cidx];
    }
    s += __shfl_xor(s, 32); s += __shfl_xor(s, 16); s += __shfl_xor(s, 8);
    s += __shfl_xor(s, 4);  s += __shfl_xor(s, 2);  s += __shfl_xor(s, 1);
    if (lane == 0){
      float a = s + b_c[0];
      float cz = 1.f/(1.f + expf(-a));   // precise libm for f32 output
      out[DF + r] = cz;
      out[DF + NN + r] = (cz > 0.7f) ? 1.f : 0.f;
    }
  } else {
    int g = b - 2048;                 // 0..767
    int col = (g % 3)*256 + threadIdx.x;
    int r0 = (g / 3)*32;              // 256 chunks x 32 rows
    float s = 0.f;
    for (int rb = 0; rb < 32; rb += 8){
      unsigned short hb[8];
      #pragma unroll
      for (int j = 0; j < 8; j++) hb[j] = h[(size_t)(r0+rb+j)*DF + col];
      #pragma unroll
      for (int j = 0; j < 8; j++) s += bf2f(hb[j]);
    }
    atomicAdd(&out[col], s * (1.f/8192.f));
  }
}

// ---------------- launch ----------------
extern "C" void kernel_launch(void* const* d_in, const int* in_sizes, int n_in,
                              void* d_out, int out_size, void* d_ws, size_t ws_size,
                              hipStream_t stream) {
  const float* node_feats = (const float*)d_in[0];
  const int*   timestamps = (const int*)d_in[1];
  const int*   ei         = (const int*)d_in[2];
  const int*   e_src = ei;
  const int*   e_dst = ei + NE_;
  const float* W_in    = (const float*)d_in[3];
  const float* conv_w  = (const float*)d_in[4];
  const float* conv_b  = (const float*)d_in[5];
  const float* W_xproj = (const float*)d_in[6];
  const float* W_dt    = (const float*)d_in[7];
  const float* b_dt    = (const float*)d_in[8];
  const float* A_log   = (const float*)d_in[9];
  const float* D_param = (const float*)d_in[10];
  const float* W_out   = (const float*)d_in[11];
  const float* Wg      = (const float*)d_in[12];
  const float* bg      = (const float*)d_in[13];
  const float* W_c     = (const float*)d_in[14];
  const float* b_c     = (const float*)d_in[15];
  float* out = (float*)d_out;

  char* ws = (char*)d_ws;
  size_t off = 0;
  auto alloc = [&](size_t bytes) -> char* {
    char* p = ws + off; off += (bytes + 255) & ~(size_t)255; return p;
  };
  unsigned short* WinT   = (unsigned short*)alloc((size_t)3072*768*2);
  unsigned short* WxT    = (unsigned short*)alloc((size_t)128*1536*2);
  unsigned short* WdtT   = (unsigned short*)alloc((size_t)1536*64*2);
  unsigned short* WoutT  = (unsigned short*)alloc((size_t)768*1536*2);
  unsigned short* WgT    = (unsigned short*)alloc((size_t)3*768*768*2);
  unsigned short* seq    = (unsigned short*)alloc((size_t)NN*DF*2);
  unsigned short* xz     = (unsigned short*)alloc((size_t)NN*3072*2);
  unsigned short* ubuf   = (unsigned short*)alloc((size_t)NN*DIM*2);
  float*          dbc    = (float*)alloc((size_t)NN*128*4);
  unsigned short* dt48   = (unsigned short*)alloc((size_t)NN*64*2);
  unsigned short* deltaB = (unsigned short*)alloc((size_t)NN*DIM*2);
  unsigned short* ybuf   = (unsigned short*)alloc((size_t)NN*DIM*2);
  unsigned short* hbuf   = (unsigned short*)alloc((size_t)NN*DF*2);
  unsigned short* mbuf   = (unsigned short*)alloc((size_t)NN*DF*2);
  unsigned char*  hq     = (unsigned char*)alloc((size_t)NN*DF);
  int*   pos    = (int*)alloc((size_t)NN*4);
  int*   degS   = (int*)alloc((size_t)2*NN*4);
  int*   degD   = degS + NN;
  float* normS  = (float*)alloc((size_t)NN*4);
  float* normD  = (float*)alloc((size_t)NN*4);
  int*   rowp   = (int*)alloc((size_t)(NN+1)*4);
  int*   cursor = (int*)alloc((size_t)NN*4);
  int*   csr    = (int*)alloc((size_t)NE_*4);

  // scan summaries: hend aliases seq (dead after G1); aprod aliases mbuf
  // (first written by k_aggregate, after scanB consumed aprod)
  float* hend  = (float*)seq;
  float* aprod = (float*)mbuf;

  // 1. weight prep (LDS-tiled transpose) + zero-init (pos/degS+degD/out[0:768])
  k_prep<<<1465, 256, 0, stream>>>(W_in, W_xproj, W_dt, W_out, Wg,
                                   WinT, WxT, WdtT, WoutT, WgT,
                                   pos, degS, out);
  // 2. rank + degree count
  k_rank_deg<<<2048, 256, 0, stream>>>(timestamps, pos, e_src, e_dst, degS, degD);
  // 3. norms + rowptr
  k_graphfix<<<9, 1024, 0, stream>>>(degS, degD, normS, normD, rowp, cursor);
  // 4. gather + csr fill
  k_scatter<<<NN + 1024, 256, 0, stream>>>(node_feats, pos, seq, e_src, e_dst, cursor, csr);

  // G1: xz = seq @ W_in
  k_gemm<0><<<64*24, 256, 0, stream>>>(seq, WinT, 3072, 768, 768, 768,
                                       nullptr, 0, xz, 3072, nullptr, nullptr, nullptr, nullptr);
  // conv + silu -> u (sliding-window)
  k_conv_silu<<<dim3(6, NN/CT), 256, 0, stream>>>(xz, conv_w, conv_b, ubuf);
  // G2: dbc = u @ W_xproj; also dt48
  k_gemm<1><<<64*1, 256, 0, stream>>>(ubuf, WxT, 128, 1536, 1536, 1536,
                                      dbc, 128, nullptr, 0, nullptr, dt48, nullptr, nullptr);
  // G3: delta = softplus(...) -> bf16
  k_gemm<2><<<64*12, 256, 0, stream>>>(dt48, WdtT, 1536, 64, 64, 64,
                                       nullptr, 0, deltaB, 1536, b_dt, nullptr, nullptr, nullptr);
  // scan: single sequential pass + combine + parallel correction
  k_scanA<<<dim3(DIM/256, NCH), 256, 0, stream>>>(deltaB, ubuf, dbc, A_log, D_param, hend, aprod, ybuf);
  k_scanB<<<96, 256, 0, stream>>>(hend, aprod);
  k_scanCorr<<<dim3(DIM/256, NCH), 256, 0, stream>>>(deltaB, xz, dbc, A_log, hend, ybuf);
  // G4: h = y @ W_out -> fp8 (normS-prescaled)
  k_gemm<5><<<64*6, 256, 0, stream>>>(ybuf, WoutT, 768, 1536, 1536, 1536,
                                      nullptr, 0, nullptr, 768, nullptr, nullptr, hq, normS);
  // 3 GCN layers
  k_aggregate<<<NN, 192, 0, stream>>>(hq, rowp, csr, normD, mbuf);
  k_gemm<4><<<64*6, 256, 0, stream>>>(mbuf, WgT, 768, 768, 768, 768,
                                      nullptr, 0, nullptr, 768, bg, nullptr, hq, normS);
  k_aggregate<<<NN, 192, 0, stream>>>(hq, rowp, csr, normD, mbuf);
  k_gemm<4><<<64*6, 256, 0, stream>>>(mbuf, WgT + (size_t)768*768, 768, 768, 768, 768,
                                      nullptr, 0, nullptr, 768, bg + 768, nullptr, hq, normS);
  k_aggregate<<<NN, 192, 0, stream>>>(hq, rowp, csr, normD, mbuf);
  k_gemm<3><<<64*6, 256, 0, stream>>>(mbuf, WgT + (size_t)2*768*768, 768, 768, 768, 768,
                                      nullptr, 0, hbuf, 768, bg + 2*768, nullptr, nullptr, nullptr);
  // finals (causal + graph_feat)
  k_final<<<2816, 256, 0, stream>>>(hbuf, W_c, b_c, out);
}